// Round 10
// baseline (451.275 us; speedup 1.0000x reference)
//
#include <hip/hip_runtime.h>
#include <hip/hip_bf16.h>
#include <math.h>

#define B_ 8
#define D_ 60
#define N_ 1024
#define K_ 20
#define P1_ 8192      // B*N
#define P2_ 163840    // B*N*K

typedef __attribute__((ext_vector_type(8))) short bf16x8;
typedef __attribute__((ext_vector_type(4))) short bf16x4;
typedef __attribute__((ext_vector_type(4))) float f32x4;

__device__ inline float b2f(short s) { return __uint_as_float(((unsigned)(unsigned short)s) << 16); }
__device__ inline short f2b(float f) { __hip_bfloat16 h = __float2bfloat16(f); return *(short*)&h; }
// order-preserving float<->uint key (for atomicMax on float values)
__device__ inline unsigned fenc(float f) { unsigned b = __float_as_uint(f); return (b & 0x80000000u) ? ~b : (b | 0x80000000u); }
__device__ inline float fdec(unsigned k) { return __uint_as_float((k & 0x80000000u) ? (k ^ 0x80000000u) : ~k); }

// ---- workspace layout (bytes), all 256-aligned ----
#define OFF_IDX   0ull          // int[P1][20] = 655360
#define OFF_XX    655360ull     // float[P1]
#define OFF_STATS 688128ull     // A[1792], B[1792], buv[128]
#define OFF_XT    720896ull     // bf16[P1][64] = 1MB
#define OFF_WB    1769472ull    // bf16 weights (wuv at WO1)
#define OFF_XC    2662400ull    // bf16[P1][512] = 8MB
#define OFF_H5    11051008ull   // bf16[P1][256] = 4MB
#define OFF_H6    15245312ull   // bf16[P1][1024] = 16MB
#define OFF_UV    32022528ull   // fp32[P1][128] = 4MB  (U | V)
#define OFF_XR1   36216832ull   // fp32[P1][64] = 2MB   raw max layer1
#define OFF_XR2   38313984ull   // fp32[P1][64] = 2MB   raw max layer2 (plain stores)
#define OFF_XR3   40411136ull   // fp32[P1][128] = 4MB  raw max layer3 (plain stores)
#define OFF_XR4   44605440ull   // uint[P1][256] = 8MB  ordered-key max layer4 (atomics)
#define OFF_H1    52994048ull   // bf16[P2][64] = 20MB
#define OFF_H2    73965568ull   // bf16[P2][64] = 20MB
#define OFF_H3    94937088ull   // bf16[P2][128] = 40MB ; pd (33.5MB fp32) aliases here
#define OFF_PART  136880128ull  // float partial stats, max 4*1280*128*4 = 2.62MB
#define OFF_PART2 139501568ull  // float stage-2 partials, 64KB
// end ~139.6 MiB

#define WO1 0
#define WO2 8192
#define WO3 12288
#define WO4 20480
#define WO5 53248
#define WO6 184320

#define SO1 0
#define SO2 64
#define SO3 128
#define SO4 256
#define SO5 512
#define SO6 768
#define NCH_TOT 1792

// ---------------- xx[bn] = sum_d x^2 ----------------
__global__ __launch_bounds__(256) void k_xx(const float* __restrict__ x,
                                            float* __restrict__ xx) {
  int bn = blockIdx.x * 256 + threadIdx.x;
  int b = bn >> 10, n = bn & 1023;
  const float* xb = x + (size_t)b * D_ * N_ + n;
  float s = 0.f;
  for (int d = 0; d < D_; ++d) { float v = xb[(size_t)d * N_]; s += v * v; }
  xx[bn] = s;
}

// ---------------- pd[b][n][m] = 2*dot - xx_n - xx_m ; tiled fp32 ----------------
__global__ __launch_bounds__(256) void k_pd(const float* __restrict__ x,
                                            const float* __restrict__ xx,
                                            float* __restrict__ pd) {
  __shared__ float lnn[D_][64];
  __shared__ float lmm[D_][128];
  int tid = threadIdx.x;
  int m0 = blockIdx.x * 128, n0 = blockIdx.y * 64, b = blockIdx.z;
  const float* xb = x + (size_t)b * D_ * N_;
  #pragma unroll
  for (int i = 0; i < 15; ++i) {
    int idx = tid + i * 256;
    int d = idx >> 6, col = idx & 63;
    lnn[d][col] = xb[(size_t)d * N_ + n0 + col];
  }
  #pragma unroll
  for (int i = 0; i < 30; ++i) {
    int idx = tid + i * 256;
    int d = idx >> 7, col = idx & 127;
    lmm[d][col] = xb[(size_t)d * N_ + m0 + col];
  }
  __syncthreads();
  int tn = tid >> 5, tm = tid & 31;
  float acc[8][4];
  #pragma unroll
  for (int i = 0; i < 8; ++i)
    #pragma unroll
    for (int j = 0; j < 4; ++j) acc[i][j] = 0.f;
  for (int d = 0; d < D_; ++d) {
    f32x4 mv  = *(const f32x4*)&lmm[d][tm * 4];
    f32x4 nva = *(const f32x4*)&lnn[d][tn * 8];
    f32x4 nvb = *(const f32x4*)&lnn[d][tn * 8 + 4];
    #pragma unroll
    for (int i = 0; i < 4; ++i)
      #pragma unroll
      for (int j = 0; j < 4; ++j) {
        acc[i][j]     = fmaf(nva[i], mv[j], acc[i][j]);
        acc[4 + i][j] = fmaf(nvb[i], mv[j], acc[4 + i][j]);
      }
  }
  const float* xxb = xx + b * 1024;
  f32x4 xxm = *(const f32x4*)(xxb + m0 + tm * 4);
  #pragma unroll
  for (int i = 0; i < 8; ++i) {
    int n = n0 + tn * 8 + i;
    float xxn = xxb[n];
    f32x4 o;
    #pragma unroll
    for (int j = 0; j < 4; ++j) o[j] = 2.f * acc[i][j] - xxn - xxm[j];
    *(f32x4*)(pd + ((size_t)(b * 1024 + n) * 1024) + m0 + tm * 4) = o;
  }
}

// ---------------- selection: one wave per point, top-20 ----------------
__global__ __launch_bounds__(256) void k_sel(const float* __restrict__ pd,
                                             int* __restrict__ idxb) {
  int tid = threadIdx.x;
  int wave = tid >> 6, lane = tid & 63;
  int bn = blockIdx.x * 4 + wave;
  const float* row = pd + (size_t)bn * 1024;
  int mbase = lane * 16;
  f32x4 r0 = *(const f32x4*)(row + mbase);
  f32x4 r1 = *(const f32x4*)(row + mbase + 4);
  f32x4 r2 = *(const f32x4*)(row + mbase + 8);
  f32x4 r3 = *(const f32x4*)(row + mbase + 12);
  float v[16];
  #pragma unroll
  for (int j = 0; j < 4; ++j) { v[j] = r0[j]; v[4 + j] = r1[j]; v[8 + j] = r2[j]; v[12 + j] = r3[j]; }
  int* outp = idxb + (size_t)bn * K_;
  for (int kk = 0; kk < K_; ++kk) {
    float bv = v[0]; int bj = 0;
    #pragma unroll
    for (int j = 1; j < 16; ++j)
      if (v[j] > bv) { bv = v[j]; bj = j; }
    int bi = mbase + bj;
    #pragma unroll
    for (int off = 1; off < 64; off <<= 1) {
      float ov = __shfl_xor(bv, off);
      int   oi = __shfl_xor(bi, off);
      if (ov > bv || (ov == bv && oi < bi)) { bv = ov; bi = oi; }
    }
    if (lane == 0) outp[kk] = bi;
    #pragma unroll
    for (int j = 0; j < 16; ++j)
      if (bi == mbase + j) v[j] = -INFINITY;
  }
}

// ---------------- xt: [B][60][N] fp32 -> [P1][64] bf16 (pad 4 zeros) ----------------
__global__ __launch_bounds__(256) void k_xt(const float* __restrict__ x,
                                            short* __restrict__ xt) {
  int bn = blockIdx.x * 256 + threadIdx.x;
  int b = bn >> 10, n = bn & 1023;
  const float* xb = x + (size_t)b * D_ * N_ + n;
  short* row = xt + (size_t)bn * 64;
  for (int c = 0; c < 60; ++c) row[c] = f2b(xb[(size_t)c * N_]);
  row[60] = 0; row[61] = 0; row[62] = 0; row[63] = 0;
}

// ---------------- wuv: rows 0..63 = W1a (nbr-ctr part), 64..127 = W1b - W1a ----------------
__global__ __launch_bounds__(256) void k_wuv(const float* __restrict__ w1,
                                             const float* __restrict__ b1,
                                             short* __restrict__ wuv,
                                             float* __restrict__ buv) {
  int t = blockIdx.x * 256 + threadIdx.x;  // 8192
  int o = t >> 6, c = t & 63;
  float v = 0.f;
  if (o < 64) { if (c < 60) v = w1[o * 120 + c]; }
  else { int o2 = o - 64; if (c < 60) v = w1[o2 * 120 + 60 + c] - w1[o2 * 120 + c]; }
  wuv[t] = f2b(v);
  if (t < 128) buv[t] = (t < 64) ? 0.f : b1[t - 64];
}

// ---------------- convert w2..w6 fp32 -> bf16 ----------------
__global__ __launch_bounds__(256) void k_wcvt(const float* __restrict__ w2,
                                              const float* __restrict__ w3,
                                              const float* __restrict__ w4,
                                              const float* __restrict__ w5,
                                              const float* __restrict__ w6,
                                              short* __restrict__ wbase) {
  int t = blockIdx.x * 256 + threadIdx.x;
  if (t < 4096) wbase[WO2 + t] = f2b(w2[t]);
  else if (t < 12288) wbase[WO3 + (t - 4096)] = f2b(w3[t - 4096]);
  else if (t < 45056) wbase[WO4 + (t - 12288)] = f2b(w4[t - 12288]);
  else if (t < 176128) wbase[WO5 + (t - 45056)] = f2b(w5[t - 45056]);
  else if (t < 438272) wbase[WO6 + (t - 176128)] = f2b(w6[t - 176128]);
}

// ---------------- standalone BN+lrelu, in place on bf16 [rows][C] ----------------
template <int C>
__global__ __launch_bounds__(256) void k_act(short* __restrict__ h,
                                             const float* __restrict__ A,
                                             const float* __restrict__ Bp) {
  int t = blockIdx.x * 256 + threadIdx.x;
  int c0 = (t & (C / 8 - 1)) * 8;
  bf16x8 v = *(bf16x8*)(h + (size_t)t * 8);
  f32x4 a0 = *(const f32x4*)(A + c0), a1 = *(const f32x4*)(A + c0 + 4);
  f32x4 b0 = *(const f32x4*)(Bp + c0), b1 = *(const f32x4*)(Bp + c0 + 4);
  #pragma unroll
  for (int j = 0; j < 8; ++j) {
    float aj = j < 4 ? a0[j] : a1[j - 4];
    float bj = j < 4 ? b0[j] : b1[j - 4];
    float f = b2f(v[j]) * aj + bj;
    f = f >= 0.f ? f : 0.2f * f;
    v[j] = f2b(f);
  }
  *(bf16x8*)(h + (size_t)t * 8) = v;
}

// ---------------- streaming max-over-k + BN stat partials from stored h ----------------
template <int C>
__global__ __launch_bounds__(256) void k_maxh(const short* __restrict__ h,
                                              float* __restrict__ xrf,
                                              float* __restrict__ part) {
  constexpr int TPP = C / 8;            // threads per point
  constexpr int PTS = 256 / TPP;        // points per block
  __shared__ float lsS[256 * 8];
  __shared__ float lsQ[256 * 8];
  int tid = threadIdx.x;
  int lp = tid / TPP;
  int c0 = (tid % TPP) * 8;
  int pt = blockIdx.x * PTS + lp;
  const short* hp = h + (size_t)pt * K_ * C + c0;
  float mx[8], sm[8], sq[8];
  #pragma unroll
  for (int j = 0; j < 8; ++j) { mx[j] = -INFINITY; sm[j] = 0.f; sq[j] = 0.f; }
  for (int k = 0; k < K_; ++k) {
    bf16x8 v = *(const bf16x8*)(hp + (size_t)k * C);
    #pragma unroll
    for (int j = 0; j < 8; ++j) {
      float f = b2f(v[j]);
      mx[j] = fmaxf(mx[j], f);
      sm[j] += f; sq[j] += f * f;
    }
  }
  f32x4 m0, m1;
  #pragma unroll
  for (int j = 0; j < 4; ++j) { m0[j] = mx[j]; m1[j] = mx[4 + j]; }
  *(f32x4*)(xrf + (size_t)pt * C + c0) = m0;
  *(f32x4*)(xrf + (size_t)pt * C + c0 + 4) = m1;
  #pragma unroll
  for (int j = 0; j < 8; ++j) { lsS[tid * 8 + j] = sm[j]; lsQ[tid * 8 + j] = sq[j]; }
  __syncthreads();
  if (tid < C) {
    int ci = tid >> 3, e = tid & 7;
    float s = 0.f, q = 0.f;
    #pragma unroll
    for (int p = 0; p < PTS; ++p) {
      s += lsS[(p * TPP + ci) * 8 + e];
      q += lsQ[(p * TPP + ci) * 8 + e];
    }
    size_t base = ((size_t)(tid >> 6) * gridDim.x + blockIdx.x) * 128;
    part[base + (tid & 63)] = s;
    part[base + 64 + (tid & 63)] = q;
  }
}

// ---------------- tiled MFMA GEMM: block 128p x 64co ----------------
// A LDS-staged (PANEL=64, PK=72 proven stride); W fragments loaded per-lane
// DIRECTLY from global (L2-hot slab) into MFMA registers -- no ldsW. This
// removes 10 of 18 DS b128 ops per panel and shrinks LDS to ~19KB (8 blk/CU).
// WMAX (layer 4) stages acc fp32 in two 64-row halves inside the A-panel LDS
// region; STATS piggybacks column sums/ssq on the same staged buffer.
template <int K, int COUT, bool APPLY, bool STATS, bool WMAX, bool HSTORE, bool F32OUT>
__global__ __launch_bounds__(256) void k_gemm(const short* __restrict__ in,
                                              const short* __restrict__ wb,
                                              const float* __restrict__ bias,
                                              const float* __restrict__ Ain,
                                              const float* __restrict__ Bin,
                                              float* __restrict__ part,
                                              short* __restrict__ out,
                                              unsigned* __restrict__ umax) {
  constexpr int PANEL = 64;
  constexpr int NPAN = K / PANEL;
  constexpr int CPR = PANEL / 8;            // 16B chunks per panel row (=8)
  constexpr int CSH = 3;
  constexpr int PK = PANEL + 8;             // padded LDS row stride (72 elements)
  constexpr int KS = PANEL / 32;            // MFMA k-steps per panel (=2)
  constexpr int NX = COUT / 64;             // co-chunks (gridDim.x)
  constexpr int SA = 128 * PK * 2;          // 18432 (holds [64][68] fp32 max stage)
  __shared__ __align__(16) char smem[SA + 512];
  short* ldsA = (short*)smem;
  float* ls = (float*)(smem + SA);
  int tid = threadIdx.x;
  int w = tid >> 6, lane = tid & 63;
  int ln = lane & 15, quad = lane >> 4;
  // XCD-bijective swizzle: all co-chunks of a row-panel land consecutively on one XCD
  int bid = blockIdx.y * NX + blockIdx.x;
  int tot = NX * gridDim.y;
  int gid = (bid & 7) * (tot >> 3) + (bid >> 3);
  int bxx = gid % NX;
  int rp = gid / NX;
  int co0 = bxx * 64;
  const short* srcA = in + (size_t)rp * 128 * K;
  // per-lane W fragment base: row (co0 + m*16 + ln), col (kp + ks*32 + quad*8)
  const short* srcW = wb + ((size_t)(co0 + ln)) * K + quad * 8;

  f32x4 acc[4][2];
  #pragma unroll
  for (int m = 0; m < 4; ++m)
    #pragma unroll
    for (int t = 0; t < 2; ++t) acc[m][t] = (f32x4){0.f, 0.f, 0.f, 0.f};

  for (int pan = 0; pan < NPAN; ++pan) {
    int kp = pan * PANEL;
    if (pan) __syncthreads();
    // stage input panel 128 x PANEL into LDS (coalesced: 16B/lane)
    #pragma unroll
    for (int i = 0; i < CPR / 2; ++i) {
      int g = i * 256 + tid;
      int row = g >> CSH, c = g & (CPR - 1);
      bf16x8 v = *(const bf16x8*)(srcA + (size_t)row * K + kp + c * 8);
      if (APPLY) {
        f32x4 a0 = *(const f32x4*)(Ain + kp + c * 8);
        f32x4 a1 = *(const f32x4*)(Ain + kp + c * 8 + 4);
        f32x4 b0 = *(const f32x4*)(Bin + kp + c * 8);
        f32x4 b1 = *(const f32x4*)(Bin + kp + c * 8 + 4);
        #pragma unroll
        for (int j = 0; j < 8; ++j) {
          float aj = j < 4 ? a0[j] : a1[j - 4];
          float bj = j < 4 ? b0[j] : b1[j - 4];
          float f = b2f(v[j]) * aj + bj;
          f = f >= 0.f ? f : 0.2f * f;
          v[j] = f2b(f);
        }
      }
      *(bf16x8*)(ldsA + row * PK + c * 8) = v;
    }
    __syncthreads();
    #pragma unroll
    for (int ks = 0; ks < KS; ++ks) {
      bf16x8 a[4], bfr[2];
      #pragma unroll
      for (int m = 0; m < 4; ++m)
        a[m] = *(const bf16x8*)(srcW + (size_t)m * 16 * K + kp + ks * 32);
      #pragma unroll
      for (int t = 0; t < 2; ++t)
        bfr[t] = *(const bf16x8*)(ldsA + (w * 32 + t * 16 + ln) * PK + ks * 32 + quad * 8);
      #pragma unroll
      for (int m = 0; m < 4; ++m)
        #pragma unroll
        for (int t = 0; t < 2; ++t)
          acc[m][t] = __builtin_amdgcn_mfma_f32_16x16x32_bf16(a[m], bfr[t], acc[m][t], 0, 0, 0);
    }
  }
  // epilogue: bias
  #pragma unroll
  for (int m = 0; m < 4; ++m) {
    f32x4 bs = *(const f32x4*)(bias + co0 + m * 16 + quad * 4);
    #pragma unroll
    for (int t = 0; t < 2; ++t)
      #pragma unroll
      for (int r = 0; r < 4; ++r) acc[m][t][r] += bs[r];
  }
  if (HSTORE) {
    #pragma unroll
    for (int m = 0; m < 4; ++m)
      #pragma unroll
      for (int t = 0; t < 2; ++t) {
        int p = rp * 128 + w * 32 + t * 16 + ln;
        if (F32OUT) {
          *(f32x4*)((float*)out + (size_t)p * COUT + co0 + m * 16 + quad * 4) = acc[m][t];
        } else {
          bf16x4 o;
          #pragma unroll
          for (int r = 0; r < 4; ++r) o[r] = f2b(acc[m][t][r]);
          *(bf16x4*)(out + (size_t)p * COUT + co0 + m * 16 + quad * 4) = o;
        }
      }
  }
  // stats via shfl reduce (layers 5/6: STATS without WMAX)
  if (STATS && !WMAX) {
    __syncthreads();
    if (tid < 128) ls[tid] = 0.f;
    __syncthreads();
    #pragma unroll
    for (int m = 0; m < 4; ++m)
      #pragma unroll
      for (int r = 0; r < 4; ++r) {
        float v0 = acc[m][0][r], v1 = acc[m][1][r];
        float s = v0 + v1, ss = v0 * v0 + v1 * v1;
        #pragma unroll
        for (int off = 1; off < 16; off <<= 1) {
          s += __shfl_xor(s, off); ss += __shfl_xor(ss, off);
        }
        if (ln == 0) {
          atomicAdd(&ls[m * 16 + quad * 4 + r], s);
          atomicAdd(&ls[64 + m * 16 + quad * 4 + r], ss);
        }
      }
    __syncthreads();
    if (tid < 128)
      part[((size_t)bxx * gridDim.y + rp) * 128 + tid] = ls[tid];
  }
  // fused raw max over k (+ stats from the same staged buffer when STATS)
  if (WMAX) {
    float* m32 = (float*)smem;  // [64][68] fp32, reuses A-panel region
    if (STATS && tid < 128) ls[tid] = 0.f;
    #pragma unroll
    for (int half = 0; half < 2; ++half) {
      __syncthreads();
      if ((w >> 1) == half) {
        int lw = w & 1;
        #pragma unroll
        for (int m = 0; m < 4; ++m)
          #pragma unroll
          for (int t = 0; t < 2; ++t)
            *(f32x4*)(m32 + (size_t)(lw * 32 + t * 16 + ln) * 68 + m * 16 + quad * 4) = acc[m][t];
      }
      __syncthreads();
      int col = tid & 63;
      {
        int r0 = rp * 128 + half * 64;
        int pt0 = r0 / 20;
        int lpt = tid >> 6;                 // 4 candidate groups x 64 cols
        int ptg = pt0 + lpt;
        int rs = ptg * 20 - r0, re = rs + 20;
        rs = rs < 0 ? 0 : rs;
        re = re > 64 ? 64 : re;
        if (rs < re) {
          float mv = -INFINITY;
          for (int r = rs; r < re; ++r) mv = fmaxf(mv, m32[r * 68 + col]);
          atomicMax(&umax[(size_t)ptg * COUT + co0 + col], fenc(mv));
        }
      }
      if (STATS) {
        int q = tid >> 6;                   // row-quarter of this half
        float s = 0.f, qq = 0.f;
        #pragma unroll
        for (int r = 0; r < 16; ++r) {
          float v = m32[(q * 16 + r) * 68 + col];
          s += v; qq += v * v;
        }
        atomicAdd(&ls[col], s);
        atomicAdd(&ls[64 + col], qq);
      }
    }
    if (STATS) {
      __syncthreads();
      if (tid < 128)
        part[((size_t)bxx * gridDim.y + rp) * 128 + tid] = ls[tid];
    }
  }
}

// ---------------- expand: h1[(n,k),c] = U[nbr,c] + V[n,c]; fused stats + max ----------------
__global__ __launch_bounds__(256) void k_expand(const float* __restrict__ UVf,
                                                const int* __restrict__ idxb,
                                                short* __restrict__ h1,
                                                float* __restrict__ xr1,
                                                float* __restrict__ part) {
  int tid = threadIdx.x;
  int lp = tid >> 4;
  int c0 = (tid & 15) * 4;
  int pt = blockIdx.x * 16 + lp;
  int base = (pt >> 10) << 10;
  f32x4 V = *(const f32x4*)(UVf + (size_t)pt * 128 + 64 + c0);
  f32x4 sum = (f32x4){0.f, 0.f, 0.f, 0.f};
  f32x4 ssq = (f32x4){0.f, 0.f, 0.f, 0.f};
  f32x4 mx = (f32x4){-INFINITY, -INFINITY, -INFINITY, -INFINITY};
  const int* ip = idxb + (size_t)pt * K_;
  size_t hb = (size_t)pt * K_ * 64 + c0;
  for (int k = 0; k < K_; ++k) {
    int nb = base + ip[k];
    f32x4 U = *(const f32x4*)(UVf + (size_t)nb * 128 + c0);
    bf16x4 o;
    #pragma unroll
    for (int j = 0; j < 4; ++j) {
      float h = U[j] + V[j];
      mx[j] = fmaxf(mx[j], U[j]);
      sum[j] += h; ssq[j] += h * h;
      o[j] = f2b(h);
    }
    *(bf16x4*)(h1 + hb + (size_t)k * 64) = o;
  }
  f32x4 xo;
  #pragma unroll
  for (int j = 0; j < 4; ++j) xo[j] = mx[j] + V[j];
  *(f32x4*)(xr1 + (size_t)pt * 64 + c0) = xo;
  __shared__ float ls[2048];
  *(f32x4*)(ls + tid * 4) = sum;
  *(f32x4*)(ls + 1024 + tid * 4) = ssq;
  __syncthreads();
  if (tid < 32) {
    int cl = tid & 15;
    bool issq = tid >= 16;
    const float* src = ls + (issq ? 1024 : 0);
    f32x4 s = (f32x4){0.f, 0.f, 0.f, 0.f};
    #pragma unroll
    for (int g = 0; g < 16; ++g) {
      f32x4 v = *(const f32x4*)(src + (g * 16 + cl) * 4);
      s[0] += v[0]; s[1] += v[1]; s[2] += v[2]; s[3] += v[3];
    }
    *(f32x4*)(part + (size_t)blockIdx.x * 128 + (issq ? 64 : 0) + cl * 4) = s;
  }
}

// ---------------- stage-1 reduction: part[cc][NB][128] -> part2[cc][32][128] ----------------
__global__ __launch_bounds__(256) void k_red(const float* __restrict__ part, int NB,
                                             float* __restrict__ part2) {
  int cc = blockIdx.x, by = blockIdx.y;
  int tid = threadIdx.x;
  int rg = tid >> 5;
  int c4 = (tid & 31) * 4;
  int chunk = NB >> 5;
  const float* p = part + ((size_t)cc * NB + (size_t)by * chunk) * 128;
  f32x4 acc = (f32x4){0.f, 0.f, 0.f, 0.f};
  for (int r = rg; r < chunk; r += 8) {
    f32x4 v = *(const f32x4*)(p + (size_t)r * 128 + c4);
    acc[0] += v[0]; acc[1] += v[1]; acc[2] += v[2]; acc[3] += v[3];
  }
  __shared__ float lds[1024];
  *(f32x4*)(lds + tid * 4) = acc;
  __syncthreads();
  if (tid < 32) {
    f32x4 s = (f32x4){0.f, 0.f, 0.f, 0.f};
    #pragma unroll
    for (int g = 0; g < 8; ++g) {
      f32x4 v = *(const f32x4*)(lds + (g * 32 + tid) * 4);
      s[0] += v[0]; s[1] += v[1]; s[2] += v[2]; s[3] += v[3];
    }
    *(f32x4*)(part2 + ((size_t)cc * 32 + by) * 128 + tid * 4) = s;
  }
}

// ---------------- reduce partials -> A = g*rsqrt(var+eps), B = be - mean*A ----------------
__global__ __launch_bounds__(256) void k_bnab(const float* __restrict__ part, int NB,
                                              const float* __restrict__ g,
                                              const float* __restrict__ be,
                                              float* __restrict__ A,
                                              float* __restrict__ Bp, float inv) {
  __shared__ float red[256];
  int tid = threadIdx.x;
  int j = tid & 127, h = tid >> 7;
  const float* p = part + (size_t)blockIdx.x * NB * 128;
  float s = 0.f;
  for (int bx = h; bx < NB; bx += 2) s += p[(size_t)bx * 128 + j];
  red[tid] = s;
  __syncthreads();
  if (tid < 128) red[tid] = red[tid] + red[tid + 128];
  __syncthreads();
  if (tid < 64) {
    int c = blockIdx.x * 64 + tid;
    float m = red[tid] * inv;
    float v = red[64 + tid] * inv - m * m;
    float a = g[c] * rsqrtf(v + 1e-5f);
    A[c] = a; Bp[c] = be[c] - m * a;
  }
}

// ---------------- xcat: decode raw maxes, apply BN+lrelu, pack [P1][512] bf16 ----------------
__global__ __launch_bounds__(256) void k_xcat(const float* __restrict__ xr1,
                                              const float* __restrict__ xr2f,
                                              const float* __restrict__ xr3f,
                                              const unsigned* __restrict__ xr4,
                                              const float* __restrict__ A,
                                              const float* __restrict__ Bp,
                                              short* __restrict__ xcat) {
  int t = blockIdx.x * 256 + threadIdx.x;  // P1*128
  int p = t >> 7, cq = t & 127;
  int c0 = cq * 4;
  f32x4 v;
  if (c0 < 64) {
    v = *(const f32x4*)(xr1 + (size_t)p * 64 + c0);
  } else if (c0 < 128) {
    v = *(const f32x4*)(xr2f + (size_t)p * 64 + (c0 - 64));
  } else if (c0 < 256) {
    v = *(const f32x4*)(xr3f + (size_t)p * 128 + (c0 - 128));
  } else {
    const unsigned* src = xr4 + (size_t)p * 256;
    int cc = c0 - 256;
    #pragma unroll
    for (int j = 0; j < 4; ++j) v[j] = fdec(src[cc + j]);
  }
  f32x4 a = *(const f32x4*)(A + c0);
  f32x4 b = *(const f32x4*)(Bp + c0);
  bf16x4 o;
  #pragma unroll
  for (int j = 0; j < 4; ++j) {
    float f = v[j] * a[j] + b[j];
    f = f >= 0.f ? f : 0.2f * f;
    o[j] = f2b(f);
  }
  *(bf16x4*)(xcat + (size_t)p * 512 + c0) = o;
}

// ---------------- final: BN+lrelu bf16 [P1][1024] -> fp32 out ----------------
__global__ __launch_bounds__(256) void k_apply_out(const short* __restrict__ h,
                                                   const float* __restrict__ A,
                                                   const float* __restrict__ Bp,
                                                   float* __restrict__ out) {
  int t = blockIdx.x * 256 + threadIdx.x;
  int c0 = (t & 255) * 4;
  f32x4 a = *(const f32x4*)(A + c0);
  f32x4 b = *(const f32x4*)(Bp + c0);
  bf16x4 v = *(const bf16x4*)(h + (size_t)t * 4);
  f32x4 o;
  #pragma unroll
  for (int r = 0; r < 4; ++r) {
    float f = b2f(v[r]) * a[r] + b[r];
    o[r] = f >= 0.f ? f : 0.2f * f;
  }
  *(f32x4*)(out + (size_t)t * 4) = o;
}

extern "C" void kernel_launch(void* const* d_in, const int* in_sizes, int n_in,
                              void* d_out, int out_size, void* d_ws, size_t ws_size,
                              hipStream_t stream) {
  const float* x   = (const float*)d_in[0];
  const float* w1  = (const float*)d_in[1];
  const float* b1  = (const float*)d_in[2];
  const float* g1  = (const float*)d_in[3];
  const float* be1 = (const float*)d_in[4];
  const float* w2  = (const float*)d_in[5];
  const float* b2  = (const float*)d_in[6];
  const float* g2  = (const float*)d_in[7];
  const float* be2 = (const float*)d_in[8];
  const float* w3  = (const float*)d_in[9];
  const float* b3  = (const float*)d_in[10];
  const float* g3  = (const float*)d_in[11];
  const float* be3 = (const float*)d_in[12];
  const float* w4  = (const float*)d_in[13];
  const float* b4  = (const float*)d_in[14];
  const float* g4  = (const float*)d_in[15];
  const float* be4 = (const float*)d_in[16];
  const float* w5  = (const float*)d_in[17];
  const float* b5  = (const float*)d_in[18];
  const float* g5  = (const float*)d_in[19];
  const float* be5 = (const float*)d_in[20];
  const float* w6  = (const float*)d_in[21];
  const float* b6  = (const float*)d_in[22];
  const float* g6  = (const float*)d_in[23];
  const float* be6 = (const float*)d_in[24];
  float* out = (float*)d_out;
  char* ws = (char*)d_ws;

  int*      idxb = (int*)(ws + OFF_IDX);
  float*    xx   = (float*)(ws + OFF_XX);
  float*    Aall = (float*)(ws + OFF_STATS);
  float*    Ball = Aall + NCH_TOT;
  float*    buv  = Ball + NCH_TOT;
  short*    xt   = (short*)(ws + OFF_XT);
  short*    wbb  = (short*)(ws + OFF_WB);
  short*    xcat = (short*)(ws + OFF_XC);
  short*    h5   = (short*)(ws + OFF_H5);
  short*    h6   = (short*)(ws + OFF_H6);
  float*    UVf  = (float*)(ws + OFF_UV);
  float*    xr1  = (float*)(ws + OFF_XR1);
  float*    xr2f = (float*)(ws + OFF_XR2);
  float*    xr3f = (float*)(ws + OFF_XR3);
  unsigned* xr4  = (unsigned*)(ws + OFF_XR4);
  short*    h1   = (short*)(ws + OFF_H1);
  short*    h2   = (short*)(ws + OFF_H2);
  short*    h3   = (short*)(ws + OFF_H3);
  float*    pd    = (float*)(ws + OFF_H3);   // aliases h3; consumed before h3 written
  float*    part  = (float*)(ws + OFF_PART);
  float*    part2 = (float*)(ws + OFF_PART2);

  // init ordered-key max buffer for layer 4 only (key 0 < key(-inf))
  hipMemsetAsync(ws + OFF_XR4, 0, 8388608ull, stream);

  k_xx <<<P1_ / 256, 256, 0, stream>>>(x, xx);
  k_pd <<<dim3(8, 16, 8), 256, 0, stream>>>(x, xx, pd);
  k_sel<<<P1_ / 4, 256, 0, stream>>>(pd, idxb);
  k_xt <<<P1_ / 256, 256, 0, stream>>>(x, xt);
  k_wuv<<<32, 256, 0, stream>>>(w1, b1, wbb + WO1, buv);
  k_wcvt<<<1712, 256, 0, stream>>>(w2, w3, w4, w5, w6, wbb);

  // layer 1 factorized: UV[P1][128] fp32 = [W1a·x | (W1b-W1a)·x + b1]
  k_gemm<64, 128, false, false, false, true, true><<<dim3(2, 64), 256, 0, stream>>>(
      xt, wbb + WO1, buv, nullptr, nullptr, nullptr, (short*)UVf, nullptr);
  // expand: h1 = U[nbr]+V, fused stats partials + raw max -> xr1
  k_expand<<<P1_ / 16, 256, 0, stream>>>(UVf, idxb, h1, xr1, part);
  k_red <<<dim3(1, 32), 256, 0, stream>>>(part, P1_ / 16, part2);
  k_bnab<<<1, 256, 0, stream>>>(part2, 32, g1, be1, Aall + SO1, Ball + SO1, 1.f / P2_);

  // layer 2: act(h1) x w2 -> h2 (pure GEMM, epilogue offloaded to k_maxh)
  k_gemm<64, 64, true, false, false, true, false><<<dim3(1, P2_ / 128), 256, 0, stream>>>(
      h1, wbb + WO2, b2, Aall + SO1, Ball + SO1, nullptr, h2, nullptr);
  k_maxh<64><<<P1_ / 32, 256, 0, stream>>>(h2, xr2f, part);
  k_red <<<dim3(1, 32), 256, 0, stream>>>(part, P1_ / 32, part2);
  k_bnab<<<1, 256, 0, stream>>>(part2, 32, g2, be2, Aall + SO2, Ball + SO2, 1.f / P2_);

  // layer 3: act(h2) x w3 -> h3 (pure GEMM, epilogue offloaded to k_maxh)
  k_gemm<64, 128, true, false, false, true, false><<<dim3(2, P2_ / 128), 256, 0, stream>>>(
      h2, wbb + WO3, b3, Aall + SO2, Ball + SO2, nullptr, h3, nullptr);
  k_maxh<128><<<P1_ / 16, 256, 0, stream>>>(h3, xr3f, part);
  k_red <<<dim3(2, 32), 256, 0, stream>>>(part, P1_ / 16, part2);
  k_bnab<<<2, 256, 0, stream>>>(part2, 32, g3, be3, Aall + SO3, Ball + SO3, 1.f / P2_);

  // activate h3 once (in place) so layer 4 stages with zero per-element VALU
  k_act<128><<<P2_ * 128 / 2048, 256, 0, stream>>>(h3, Aall + SO3, Ball + SO3);

  // layer 4: act(h3) x w4 -> NO h4 store; fused raw max + stats (from staged buffer)
  k_gemm<128, 256, false, true, true, false, false><<<dim3(4, P2_ / 128), 256, 0, stream>>>(
      h3, wbb + WO4, b4, nullptr, nullptr, part, nullptr, xr4);
  k_red <<<dim3(4, 32), 256, 0, stream>>>(part, P2_ / 128, part2);
  k_bnab<<<4, 256, 0, stream>>>(part2, 32, g4, be4, Aall + SO4, Ball + SO4, 1.f / P2_);

  // assemble xcat from raw maxes with BN+lrelu
  k_xcat<<<P1_ * 128 / 256, 256, 0, stream>>>(xr1, xr2f, xr3f, xr4, Aall, Ball, xcat);

  // layer 5: xcat x w5 -> h5 + stats (NB=64: direct)
  k_gemm<512, 256, false, true, false, true, false><<<dim3(4, P1_ / 128), 256, 0, stream>>>(
      xcat, wbb + WO5, b5, nullptr, nullptr, part, h5, nullptr);
  k_bnab<<<4, 256, 0, stream>>>(part, P1_ / 128, g5, be5, Aall + SO5, Ball + SO5, 1.f / P1_);

  // activate h5 once (in place) so layer 6 stages with zero per-element VALU
  k_act<256><<<P1_ * 256 / 2048, 256, 0, stream>>>(h5, Aall + SO5, Ball + SO5);

  // layer 6: act(h5) x w6 -> h6 + stats
  k_gemm<256, 1024, false, true, false, true, false><<<dim3(16, P1_ / 128), 256, 0, stream>>>(
      h5, wbb + WO6, b6, nullptr, nullptr, part, h6, nullptr);
  k_bnab<<<16, 256, 0, stream>>>(part, P1_ / 128, g6, be6, Aall + SO6, Ball + SO6, 1.f / P1_);
  k_apply_out<<<P1_ * 256 / 256, 256, 0, stream>>>(h6, Aall + SO6, Ball + SO6, out);

  (void)in_sizes; (void)n_in; (void)out_size; (void)ws_size;
}

// Round 11
// 405.772 us; speedup vs baseline: 1.1121x; 1.1121x over previous
//
#include <hip/hip_runtime.h>
#include <hip/hip_bf16.h>
#include <math.h>

#define B_ 8
#define D_ 60
#define N_ 1024
#define K_ 20
#define P1_ 8192      // B*N
#define P2_ 163840    // B*N*K

typedef __attribute__((ext_vector_type(8))) short bf16x8;
typedef __attribute__((ext_vector_type(4))) short bf16x4;
typedef __attribute__((ext_vector_type(4))) float f32x4;

__device__ inline float b2f(short s) { return __uint_as_float(((unsigned)(unsigned short)s) << 16); }
__device__ inline short f2b(float f) { __hip_bfloat16 h = __float2bfloat16(f); return *(short*)&h; }
// order-preserving float<->uint key (for atomicMax on float values)
__device__ inline unsigned fenc(float f) { unsigned b = __float_as_uint(f); return (b & 0x80000000u) ? ~b : (b | 0x80000000u); }
__device__ inline float fdec(unsigned k) { return __uint_as_float((k & 0x80000000u) ? (k ^ 0x80000000u) : ~k); }

// async global->LDS, 16B per lane; lds dest = wave-uniform base + lane*16
__device__ __forceinline__ void gl16(const short* g, short* l) {
  __builtin_amdgcn_global_load_lds(
      (const __attribute__((address_space(1))) unsigned int*)g,
      (__attribute__((address_space(3))) unsigned int*)l, 16, 0, 0);
}

// ---- workspace layout (bytes), all 256-aligned ----
#define OFF_IDX   0ull          // int[P1][20] = 655360
#define OFF_XX    655360ull     // float[P1]
#define OFF_STATS 688128ull     // A[1792], B[1792], buv[128]
#define OFF_XT    720896ull     // bf16[P1][64] = 1MB
#define OFF_WB    1769472ull    // bf16 weights (wuv at WO1)
#define OFF_XC    2662400ull    // bf16[P1][512] = 8MB
#define OFF_H5    11051008ull   // bf16[P1][256] = 4MB
#define OFF_H6    15245312ull   // bf16[P1][1024] = 16MB
#define OFF_UV    32022528ull   // fp32[P1][128] = 4MB  (U | V)
#define OFF_XR1   36216832ull   // fp32[P1][64] = 2MB   raw max layer1
#define OFF_XR2   38313984ull   // fp32[P1][64] = 2MB   raw max layer2 (plain stores)
#define OFF_XR3   40411136ull   // fp32[P1][128] = 4MB  raw max layer3 (plain stores)
#define OFF_XR4   44605440ull   // uint[P1][256] = 8MB  ordered-key max layer4 (atomics)
#define OFF_H1    52994048ull   // bf16[P2][64] = 20MB
#define OFF_H2    73965568ull   // bf16[P2][64] = 20MB
#define OFF_H3    94937088ull   // bf16[P2][128] = 40MB ; pd (33.5MB fp32) aliases here
#define OFF_PART  136880128ull  // float partial stats, max 4*1280*128*4 = 2.62MB
#define OFF_PART2 139501568ull  // float stage-2 partials, 64KB
// end ~139.6 MiB

#define WO1 0
#define WO2 8192
#define WO3 12288
#define WO4 20480
#define WO5 53248
#define WO6 184320

#define SO1 0
#define SO2 64
#define SO3 128
#define SO4 256
#define SO5 512
#define SO6 768
#define NCH_TOT 1792

// ---------------- xx[bn] = sum_d x^2 ----------------
__global__ __launch_bounds__(256) void k_xx(const float* __restrict__ x,
                                            float* __restrict__ xx) {
  int bn = blockIdx.x * 256 + threadIdx.x;
  int b = bn >> 10, n = bn & 1023;
  const float* xb = x + (size_t)b * D_ * N_ + n;
  float s = 0.f;
  for (int d = 0; d < D_; ++d) { float v = xb[(size_t)d * N_]; s += v * v; }
  xx[bn] = s;
}

// ---------------- pd[b][n][m] = 2*dot - xx_n - xx_m ; tiled fp32 ----------------
__global__ __launch_bounds__(256) void k_pd(const float* __restrict__ x,
                                            const float* __restrict__ xx,
                                            float* __restrict__ pd) {
  __shared__ float lnn[D_][64];
  __shared__ float lmm[D_][128];
  int tid = threadIdx.x;
  int m0 = blockIdx.x * 128, n0 = blockIdx.y * 64, b = blockIdx.z;
  const float* xb = x + (size_t)b * D_ * N_;
  #pragma unroll
  for (int i = 0; i < 15; ++i) {
    int idx = tid + i * 256;
    int d = idx >> 6, col = idx & 63;
    lnn[d][col] = xb[(size_t)d * N_ + n0 + col];
  }
  #pragma unroll
  for (int i = 0; i < 30; ++i) {
    int idx = tid + i * 256;
    int d = idx >> 7, col = idx & 127;
    lmm[d][col] = xb[(size_t)d * N_ + m0 + col];
  }
  __syncthreads();
  int tn = tid >> 5, tm = tid & 31;
  float acc[8][4];
  #pragma unroll
  for (int i = 0; i < 8; ++i)
    #pragma unroll
    for (int j = 0; j < 4; ++j) acc[i][j] = 0.f;
  for (int d = 0; d < D_; ++d) {
    f32x4 mv  = *(const f32x4*)&lmm[d][tm * 4];
    f32x4 nva = *(const f32x4*)&lnn[d][tn * 8];
    f32x4 nvb = *(const f32x4*)&lnn[d][tn * 8 + 4];
    #pragma unroll
    for (int i = 0; i < 4; ++i)
      #pragma unroll
      for (int j = 0; j < 4; ++j) {
        acc[i][j]     = fmaf(nva[i], mv[j], acc[i][j]);
        acc[4 + i][j] = fmaf(nvb[i], mv[j], acc[4 + i][j]);
      }
  }
  const float* xxb = xx + b * 1024;
  f32x4 xxm = *(const f32x4*)(xxb + m0 + tm * 4);
  #pragma unroll
  for (int i = 0; i < 8; ++i) {
    int n = n0 + tn * 8 + i;
    float xxn = xxb[n];
    f32x4 o;
    #pragma unroll
    for (int j = 0; j < 4; ++j) o[j] = 2.f * acc[i][j] - xxn - xxm[j];
    *(f32x4*)(pd + ((size_t)(b * 1024 + n) * 1024) + m0 + tm * 4) = o;
  }
}

// ---------------- selection: one wave per point, top-20 ----------------
__global__ __launch_bounds__(256) void k_sel(const float* __restrict__ pd,
                                             int* __restrict__ idxb) {
  int tid = threadIdx.x;
  int wave = tid >> 6, lane = tid & 63;
  int bn = blockIdx.x * 4 + wave;
  const float* row = pd + (size_t)bn * 1024;
  int mbase = lane * 16;
  f32x4 r0 = *(const f32x4*)(row + mbase);
  f32x4 r1 = *(const f32x4*)(row + mbase + 4);
  f32x4 r2 = *(const f32x4*)(row + mbase + 8);
  f32x4 r3 = *(const f32x4*)(row + mbase + 12);
  float v[16];
  #pragma unroll
  for (int j = 0; j < 4; ++j) { v[j] = r0[j]; v[4 + j] = r1[j]; v[8 + j] = r2[j]; v[12 + j] = r3[j]; }
  int* outp = idxb + (size_t)bn * K_;
  for (int kk = 0; kk < K_; ++kk) {
    float bv = v[0]; int bj = 0;
    #pragma unroll
    for (int j = 1; j < 16; ++j)
      if (v[j] > bv) { bv = v[j]; bj = j; }
    int bi = mbase + bj;
    #pragma unroll
    for (int off = 1; off < 64; off <<= 1) {
      float ov = __shfl_xor(bv, off);
      int   oi = __shfl_xor(bi, off);
      if (ov > bv || (ov == bv && oi < bi)) { bv = ov; bi = oi; }
    }
    if (lane == 0) outp[kk] = bi;
    #pragma unroll
    for (int j = 0; j < 16; ++j)
      if (bi == mbase + j) v[j] = -INFINITY;
  }
}

// ---------------- xt: [B][60][N] fp32 -> [P1][64] bf16 (pad 4 zeros) ----------------
__global__ __launch_bounds__(256) void k_xt(const float* __restrict__ x,
                                            short* __restrict__ xt) {
  int bn = blockIdx.x * 256 + threadIdx.x;
  int b = bn >> 10, n = bn & 1023;
  const float* xb = x + (size_t)b * D_ * N_ + n;
  short* row = xt + (size_t)bn * 64;
  for (int c = 0; c < 60; ++c) row[c] = f2b(xb[(size_t)c * N_]);
  row[60] = 0; row[61] = 0; row[62] = 0; row[63] = 0;
}

// ---------------- wuv: rows 0..63 = W1a (nbr-ctr part), 64..127 = W1b - W1a ----------------
__global__ __launch_bounds__(256) void k_wuv(const float* __restrict__ w1,
                                             const float* __restrict__ b1,
                                             short* __restrict__ wuv,
                                             float* __restrict__ buv) {
  int t = blockIdx.x * 256 + threadIdx.x;  // 8192
  int o = t >> 6, c = t & 63;
  float v = 0.f;
  if (o < 64) { if (c < 60) v = w1[o * 120 + c]; }
  else { int o2 = o - 64; if (c < 60) v = w1[o2 * 120 + 60 + c] - w1[o2 * 120 + c]; }
  wuv[t] = f2b(v);
  if (t < 128) buv[t] = (t < 64) ? 0.f : b1[t - 64];
}

// ---------------- convert w2..w6 fp32 -> bf16 ----------------
__global__ __launch_bounds__(256) void k_wcvt(const float* __restrict__ w2,
                                              const float* __restrict__ w3,
                                              const float* __restrict__ w4,
                                              const float* __restrict__ w5,
                                              const float* __restrict__ w6,
                                              short* __restrict__ wbase) {
  int t = blockIdx.x * 256 + threadIdx.x;
  if (t < 4096) wbase[WO2 + t] = f2b(w2[t]);
  else if (t < 12288) wbase[WO3 + (t - 4096)] = f2b(w3[t - 4096]);
  else if (t < 45056) wbase[WO4 + (t - 12288)] = f2b(w4[t - 12288]);
  else if (t < 176128) wbase[WO5 + (t - 45056)] = f2b(w5[t - 45056]);
  else if (t < 438272) wbase[WO6 + (t - 176128)] = f2b(w6[t - 176128]);
}

// ---------------- standalone BN+lrelu, in place on bf16 [rows][C] ----------------
template <int C>
__global__ __launch_bounds__(256) void k_act(short* __restrict__ h,
                                             const float* __restrict__ A,
                                             const float* __restrict__ Bp) {
  int t = blockIdx.x * 256 + threadIdx.x;
  int c0 = (t & (C / 8 - 1)) * 8;
  bf16x8 v = *(bf16x8*)(h + (size_t)t * 8);
  f32x4 a0 = *(const f32x4*)(A + c0), a1 = *(const f32x4*)(A + c0 + 4);
  f32x4 b0 = *(const f32x4*)(Bp + c0), b1 = *(const f32x4*)(Bp + c0 + 4);
  #pragma unroll
  for (int j = 0; j < 8; ++j) {
    float aj = j < 4 ? a0[j] : a1[j - 4];
    float bj = j < 4 ? b0[j] : b1[j - 4];
    float f = b2f(v[j]) * aj + bj;
    f = f >= 0.f ? f : 0.2f * f;
    v[j] = f2b(f);
  }
  *(bf16x8*)(h + (size_t)t * 8) = v;
}

// ---------------- streaming max-over-k + BN stat partials from stored h ----------------
template <int C>
__global__ __launch_bounds__(256) void k_maxh(const short* __restrict__ h,
                                              float* __restrict__ xrf,
                                              float* __restrict__ part) {
  constexpr int TPP = C / 8;            // threads per point
  constexpr int PTS = 256 / TPP;        // points per block
  __shared__ float lsS[256 * 8];
  __shared__ float lsQ[256 * 8];
  int tid = threadIdx.x;
  int lp = tid / TPP;
  int c0 = (tid % TPP) * 8;
  int pt = blockIdx.x * PTS + lp;
  const short* hp = h + (size_t)pt * K_ * C + c0;
  float mx[8], sm[8], sq[8];
  #pragma unroll
  for (int j = 0; j < 8; ++j) { mx[j] = -INFINITY; sm[j] = 0.f; sq[j] = 0.f; }
  for (int k = 0; k < K_; ++k) {
    bf16x8 v = *(const bf16x8*)(hp + (size_t)k * C);
    #pragma unroll
    for (int j = 0; j < 8; ++j) {
      float f = b2f(v[j]);
      mx[j] = fmaxf(mx[j], f);
      sm[j] += f; sq[j] += f * f;
    }
  }
  f32x4 m0, m1;
  #pragma unroll
  for (int j = 0; j < 4; ++j) { m0[j] = mx[j]; m1[j] = mx[4 + j]; }
  *(f32x4*)(xrf + (size_t)pt * C + c0) = m0;
  *(f32x4*)(xrf + (size_t)pt * C + c0 + 4) = m1;
  #pragma unroll
  for (int j = 0; j < 8; ++j) { lsS[tid * 8 + j] = sm[j]; lsQ[tid * 8 + j] = sq[j]; }
  __syncthreads();
  if (tid < C) {
    int ci = tid >> 3, e = tid & 7;
    float s = 0.f, q = 0.f;
    #pragma unroll
    for (int p = 0; p < PTS; ++p) {
      s += lsS[(p * TPP + ci) * 8 + e];
      q += lsQ[(p * TPP + ci) * 8 + e];
    }
    size_t base = ((size_t)(tid >> 6) * gridDim.x + blockIdx.x) * 128;
    part[base + (tid & 63)] = s;
    part[base + 64 + (tid & 63)] = q;
  }
}

// ---------------- tiled MFMA GEMM: block 128p x 64co, LDS-staged A and W ----------------
// APPLY=true (L2/L3): R9's proven VGPR staging with pad-72 rows.
// APPLY=false (L1/L4/L5/L6): global_load_lds width-16 staging into LINEAR PK=64 rows
// with rule-#21 both-sides XOR swizzle (source slot (lane&7)^(lane>>3), read slot
// (ks*4+quad)^(ln&7)) -- addressing correctness-verified in R5. The pre-barrier
// vmcnt(0) drain R9 already pays synchronizes the async loads for free.
// WMAX (layer 4) stages acc fp32 in two 64-row halves inside the A region;
// STATS piggybacks column sums/ssq on the same staged buffer.
template <int K, int COUT, bool APPLY, bool STATS, bool WMAX, bool HSTORE, bool F32OUT>
__global__ __launch_bounds__(256) void k_gemm(const short* __restrict__ in,
                                              const short* __restrict__ wb,
                                              const float* __restrict__ bias,
                                              const float* __restrict__ Ain,
                                              const float* __restrict__ Bin,
                                              float* __restrict__ part,
                                              short* __restrict__ out,
                                              unsigned* __restrict__ umax) {
  constexpr int PANEL = 64;
  constexpr int NPAN = K / PANEL;
  constexpr int CPR = PANEL / 8;            // 16B chunks per panel row (=8)
  constexpr int CSH = 3;
  constexpr bool GL = !APPLY;               // async gl16 path (linear + XOR swizzle)
  constexpr int PK = GL ? 64 : 72;          // LDS row stride (elements)
  constexpr int KS = PANEL / 32;            // MFMA k-steps per panel (=2)
  constexpr int NX = COUT / 64;             // co-chunks (gridDim.x)
  constexpr int ABYTES = 128 * PK * 2;
  constexpr int SA = (WMAX && ABYTES < 17664) ? 17664 : ABYTES;  // holds [64][68] f32
  __shared__ __align__(16) char smem[SA + 64 * PK * 2 + 512];
  short* ldsA = (short*)smem;
  short* ldsW = (short*)(smem + SA);
  float* ls = (float*)(smem + SA + 64 * PK * 2);
  int tid = threadIdx.x;
  int w = tid >> 6, lane = tid & 63;
  int ln = lane & 15, quad = lane >> 4;
  const int rl = lane >> 3;
  const int c16 = (lane & 7) ^ rl;          // inverse-swizzled source slot (GL)
  const int xsl = ln & 7;                   // read-side XOR (GL)
  // XCD-bijective swizzle: all co-chunks of a row-panel land consecutively on one XCD
  int bid = blockIdx.y * NX + blockIdx.x;
  int tot = NX * gridDim.y;
  int gid = (bid & 7) * (tot >> 3) + (bid >> 3);
  int bxx = gid % NX;
  int rp = gid / NX;
  int co0 = bxx * 64;
  const short* srcA = in + (size_t)rp * 128 * K;
  const short* srcW = wb + (size_t)co0 * K;

  f32x4 acc[4][2];
  #pragma unroll
  for (int m = 0; m < 4; ++m)
    #pragma unroll
    for (int t = 0; t < 2; ++t) acc[m][t] = (f32x4){0.f, 0.f, 0.f, 0.f};

  for (int pan = 0; pan < NPAN; ++pan) {
    int kp = pan * PANEL;
    if (pan) __syncthreads();
    if constexpr (GL) {
      // A: 16 chunks of 8 rows, async direct-to-LDS (linear dest, swizzled source)
      #pragma unroll
      for (int i = 0; i < 4; ++i) {
        int ch = w * 4 + i;
        gl16(srcA + (size_t)(ch * 8 + rl) * K + kp + c16 * 8, ldsA + ch * 512);
      }
      // W: 8 chunks of 8 rows
      #pragma unroll
      for (int i = 0; i < 2; ++i) {
        int ch = w * 2 + i;
        gl16(srcW + (size_t)(ch * 8 + rl) * K + kp + c16 * 8, ldsW + ch * 512);
      }
    } else {
      // stage input panel 128 x PANEL (coalesced: 16B/lane), fused BN+lrelu
      #pragma unroll
      for (int i = 0; i < CPR / 2; ++i) {
        int g = i * 256 + tid;
        int row = g >> CSH, c = g & (CPR - 1);
        bf16x8 v = *(const bf16x8*)(srcA + (size_t)row * K + kp + c * 8);
        f32x4 a0 = *(const f32x4*)(Ain + kp + c * 8);
        f32x4 a1 = *(const f32x4*)(Ain + kp + c * 8 + 4);
        f32x4 b0 = *(const f32x4*)(Bin + kp + c * 8);
        f32x4 b1 = *(const f32x4*)(Bin + kp + c * 8 + 4);
        #pragma unroll
        for (int j = 0; j < 8; ++j) {
          float aj = j < 4 ? a0[j] : a1[j - 4];
          float bj = j < 4 ? b0[j] : b1[j - 4];
          float f = b2f(v[j]) * aj + bj;
          f = f >= 0.f ? f : 0.2f * f;
          v[j] = f2b(f);
        }
        *(bf16x8*)(ldsA + row * PK + c * 8) = v;
      }
      // stage weight panel 64 x PANEL
      #pragma unroll
      for (int i = 0; i < CPR / 4; ++i) {
        int g = i * 256 + tid;
        int row = g >> CSH, c = g & (CPR - 1);
        *(bf16x8*)(ldsW + row * PK + c * 8) =
            *(const bf16x8*)(srcW + (size_t)row * K + kp + c * 8);
      }
    }
    __syncthreads();
    #pragma unroll
    for (int ks = 0; ks < KS; ++ks) {
      bf16x8 a[4], bfr[2];
      const int off = GL ? (((ks * 4 + quad) ^ xsl) * 8) : (ks * 32 + quad * 8);
      #pragma unroll
      for (int m = 0; m < 4; ++m)
        a[m] = *(const bf16x8*)(ldsW + (m * 16 + ln) * PK + off);
      #pragma unroll
      for (int t = 0; t < 2; ++t)
        bfr[t] = *(const bf16x8*)(ldsA + (w * 32 + t * 16 + ln) * PK + off);
      #pragma unroll
      for (int m = 0; m < 4; ++m)
        #pragma unroll
        for (int t = 0; t < 2; ++t)
          acc[m][t] = __builtin_amdgcn_mfma_f32_16x16x32_bf16(a[m], bfr[t], acc[m][t], 0, 0, 0);
    }
  }
  // epilogue: bias
  #pragma unroll
  for (int m = 0; m < 4; ++m) {
    f32x4 bs = *(const f32x4*)(bias + co0 + m * 16 + quad * 4);
    #pragma unroll
    for (int t = 0; t < 2; ++t)
      #pragma unroll
      for (int r = 0; r < 4; ++r) acc[m][t][r] += bs[r];
  }
  if (HSTORE) {
    #pragma unroll
    for (int m = 0; m < 4; ++m)
      #pragma unroll
      for (int t = 0; t < 2; ++t) {
        int p = rp * 128 + w * 32 + t * 16 + ln;
        if (F32OUT) {
          *(f32x4*)((float*)out + (size_t)p * COUT + co0 + m * 16 + quad * 4) = acc[m][t];
        } else {
          bf16x4 o;
          #pragma unroll
          for (int r = 0; r < 4; ++r) o[r] = f2b(acc[m][t][r]);
          *(bf16x4*)(out + (size_t)p * COUT + co0 + m * 16 + quad * 4) = o;
        }
      }
  }
  // stats via shfl reduce (layers 5/6: STATS without WMAX)
  if (STATS && !WMAX) {
    __syncthreads();
    if (tid < 128) ls[tid] = 0.f;
    __syncthreads();
    #pragma unroll
    for (int m = 0; m < 4; ++m)
      #pragma unroll
      for (int r = 0; r < 4; ++r) {
        float v0 = acc[m][0][r], v1 = acc[m][1][r];
        float s = v0 + v1, ss = v0 * v0 + v1 * v1;
        #pragma unroll
        for (int off = 1; off < 16; off <<= 1) {
          s += __shfl_xor(s, off); ss += __shfl_xor(ss, off);
        }
        if (ln == 0) {
          atomicAdd(&ls[m * 16 + quad * 4 + r], s);
          atomicAdd(&ls[64 + m * 16 + quad * 4 + r], ss);
        }
      }
    __syncthreads();
    if (tid < 128)
      part[((size_t)bxx * gridDim.y + rp) * 128 + tid] = ls[tid];
  }
  // fused raw max over k (+ stats from the same staged buffer when STATS)
  if (WMAX) {
    float* m32 = (float*)smem;  // [64][68] fp32, reuses A region
    if (STATS && tid < 128) ls[tid] = 0.f;
    #pragma unroll
    for (int half = 0; half < 2; ++half) {
      __syncthreads();
      if ((w >> 1) == half) {
        int lw = w & 1;
        #pragma unroll
        for (int m = 0; m < 4; ++m)
          #pragma unroll
          for (int t = 0; t < 2; ++t)
            *(f32x4*)(m32 + (size_t)(lw * 32 + t * 16 + ln) * 68 + m * 16 + quad * 4) = acc[m][t];
      }
      __syncthreads();
      int col = tid & 63;
      {
        int r0 = rp * 128 + half * 64;
        int pt0 = r0 / 20;
        int lpt = tid >> 6;                 // 4 candidate groups x 64 cols
        int ptg = pt0 + lpt;
        int rs = ptg * 20 - r0, re = rs + 20;
        rs = rs < 0 ? 0 : rs;
        re = re > 64 ? 64 : re;
        if (rs < re) {
          float mv = -INFINITY;
          for (int r = rs; r < re; ++r) mv = fmaxf(mv, m32[r * 68 + col]);
          atomicMax(&umax[(size_t)ptg * COUT + co0 + col], fenc(mv));
        }
      }
      if (STATS) {
        int q = tid >> 6;                   // row-quarter of this half
        float s = 0.f, qq = 0.f;
        #pragma unroll
        for (int r = 0; r < 16; ++r) {
          float v = m32[(q * 16 + r) * 68 + col];
          s += v; qq += v * v;
        }
        atomicAdd(&ls[col], s);
        atomicAdd(&ls[64 + col], qq);
      }
    }
    if (STATS) {
      __syncthreads();
      if (tid < 128)
        part[((size_t)bxx * gridDim.y + rp) * 128 + tid] = ls[tid];
    }
  }
}

// ---------------- expand: h1[(n,k),c] = U[nbr,c] + V[n,c]; fused stats + max ----------------
__global__ __launch_bounds__(256) void k_expand(const float* __restrict__ UVf,
                                                const int* __restrict__ idxb,
                                                short* __restrict__ h1,
                                                float* __restrict__ xr1,
                                                float* __restrict__ part) {
  int tid = threadIdx.x;
  int lp = tid >> 4;
  int c0 = (tid & 15) * 4;
  int pt = blockIdx.x * 16 + lp;
  int base = (pt >> 10) << 10;
  f32x4 V = *(const f32x4*)(UVf + (size_t)pt * 128 + 64 + c0);
  f32x4 sum = (f32x4){0.f, 0.f, 0.f, 0.f};
  f32x4 ssq = (f32x4){0.f, 0.f, 0.f, 0.f};
  f32x4 mx = (f32x4){-INFINITY, -INFINITY, -INFINITY, -INFINITY};
  const int* ip = idxb + (size_t)pt * K_;
  size_t hb = (size_t)pt * K_ * 64 + c0;
  for (int k = 0; k < K_; ++k) {
    int nb = base + ip[k];
    f32x4 U = *(const f32x4*)(UVf + (size_t)nb * 128 + c0);
    bf16x4 o;
    #pragma unroll
    for (int j = 0; j < 4; ++j) {
      float h = U[j] + V[j];
      mx[j] = fmaxf(mx[j], U[j]);
      sum[j] += h; ssq[j] += h * h;
      o[j] = f2b(h);
    }
    *(bf16x4*)(h1 + hb + (size_t)k * 64) = o;
  }
  f32x4 xo;
  #pragma unroll
  for (int j = 0; j < 4; ++j) xo[j] = mx[j] + V[j];
  *(f32x4*)(xr1 + (size_t)pt * 64 + c0) = xo;
  __shared__ float ls[2048];
  *(f32x4*)(ls + tid * 4) = sum;
  *(f32x4*)(ls + 1024 + tid * 4) = ssq;
  __syncthreads();
  if (tid < 32) {
    int cl = tid & 15;
    bool issq = tid >= 16;
    const float* src = ls + (issq ? 1024 : 0);
    f32x4 s = (f32x4){0.f, 0.f, 0.f, 0.f};
    #pragma unroll
    for (int g = 0; g < 16; ++g) {
      f32x4 v = *(const f32x4*)(src + (g * 16 + cl) * 4);
      s[0] += v[0]; s[1] += v[1]; s[2] += v[2]; s[3] += v[3];
    }
    *(f32x4*)(part + (size_t)blockIdx.x * 128 + (issq ? 64 : 0) + cl * 4) = s;
  }
}

// ---------------- stage-1 reduction: part[cc][NB][128] -> part2[cc][32][128] ----------------
__global__ __launch_bounds__(256) void k_red(const float* __restrict__ part, int NB,
                                             float* __restrict__ part2) {
  int cc = blockIdx.x, by = blockIdx.y;
  int tid = threadIdx.x;
  int rg = tid >> 5;
  int c4 = (tid & 31) * 4;
  int chunk = NB >> 5;
  const float* p = part + ((size_t)cc * NB + (size_t)by * chunk) * 128;
  f32x4 acc = (f32x4){0.f, 0.f, 0.f, 0.f};
  for (int r = rg; r < chunk; r += 8) {
    f32x4 v = *(const f32x4*)(p + (size_t)r * 128 + c4);
    acc[0] += v[0]; acc[1] += v[1]; acc[2] += v[2]; acc[3] += v[3];
  }
  __shared__ float lds[1024];
  *(f32x4*)(lds + tid * 4) = acc;
  __syncthreads();
  if (tid < 32) {
    f32x4 s = (f32x4){0.f, 0.f, 0.f, 0.f};
    #pragma unroll
    for (int g = 0; g < 8; ++g) {
      f32x4 v = *(const f32x4*)(lds + (g * 32 + tid) * 4);
      s[0] += v[0]; s[1] += v[1]; s[2] += v[2]; s[3] += v[3];
    }
    *(f32x4*)(part2 + ((size_t)cc * 32 + by) * 128 + tid * 4) = s;
  }
}

// ---------------- reduce partials -> A = g*rsqrt(var+eps), B = be - mean*A ----------------
__global__ __launch_bounds__(256) void k_bnab(const float* __restrict__ part, int NB,
                                              const float* __restrict__ g,
                                              const float* __restrict__ be,
                                              float* __restrict__ A,
                                              float* __restrict__ Bp, float inv) {
  __shared__ float red[256];
  int tid = threadIdx.x;
  int j = tid & 127, h = tid >> 7;
  const float* p = part + (size_t)blockIdx.x * NB * 128;
  float s = 0.f;
  for (int bx = h; bx < NB; bx += 2) s += p[(size_t)bx * 128 + j];
  red[tid] = s;
  __syncthreads();
  if (tid < 128) red[tid] = red[tid] + red[tid + 128];
  __syncthreads();
  if (tid < 64) {
    int c = blockIdx.x * 64 + tid;
    float m = red[tid] * inv;
    float v = red[64 + tid] * inv - m * m;
    float a = g[c] * rsqrtf(v + 1e-5f);
    A[c] = a; Bp[c] = be[c] - m * a;
  }
}

// ---------------- xcat: decode raw maxes, apply BN+lrelu, pack [P1][512] bf16 ----------------
__global__ __launch_bounds__(256) void k_xcat(const float* __restrict__ xr1,
                                              const float* __restrict__ xr2f,
                                              const float* __restrict__ xr3f,
                                              const unsigned* __restrict__ xr4,
                                              const float* __restrict__ A,
                                              const float* __restrict__ Bp,
                                              short* __restrict__ xcat) {
  int t = blockIdx.x * 256 + threadIdx.x;  // P1*128
  int p = t >> 7, cq = t & 127;
  int c0 = cq * 4;
  f32x4 v;
  if (c0 < 64) {
    v = *(const f32x4*)(xr1 + (size_t)p * 64 + c0);
  } else if (c0 < 128) {
    v = *(const f32x4*)(xr2f + (size_t)p * 64 + (c0 - 64));
  } else if (c0 < 256) {
    v = *(const f32x4*)(xr3f + (size_t)p * 128 + (c0 - 128));
  } else {
    const unsigned* src = xr4 + (size_t)p * 256;
    int cc = c0 - 256;
    #pragma unroll
    for (int j = 0; j < 4; ++j) v[j] = fdec(src[cc + j]);
  }
  f32x4 a = *(const f32x4*)(A + c0);
  f32x4 b = *(const f32x4*)(Bp + c0);
  bf16x4 o;
  #pragma unroll
  for (int j = 0; j < 4; ++j) {
    float f = v[j] * a[j] + b[j];
    f = f >= 0.f ? f : 0.2f * f;
    o[j] = f2b(f);
  }
  *(bf16x4*)(xcat + (size_t)p * 512 + c0) = o;
}

// ---------------- final: BN+lrelu bf16 [P1][1024] -> fp32 out ----------------
__global__ __launch_bounds__(256) void k_apply_out(const short* __restrict__ h,
                                                   const float* __restrict__ A,
                                                   const float* __restrict__ Bp,
                                                   float* __restrict__ out) {
  int t = blockIdx.x * 256 + threadIdx.x;
  int c0 = (t & 255) * 4;
  f32x4 a = *(const f32x4*)(A + c0);
  f32x4 b = *(const f32x4*)(Bp + c0);
  bf16x4 v = *(const bf16x4*)(h + (size_t)t * 4);
  f32x4 o;
  #pragma unroll
  for (int r = 0; r < 4; ++r) {
    float f = b2f(v[r]) * a[r] + b[r];
    o[r] = f >= 0.f ? f : 0.2f * f;
  }
  *(f32x4*)(out + (size_t)t * 4) = o;
}

extern "C" void kernel_launch(void* const* d_in, const int* in_sizes, int n_in,
                              void* d_out, int out_size, void* d_ws, size_t ws_size,
                              hipStream_t stream) {
  const float* x   = (const float*)d_in[0];
  const float* w1  = (const float*)d_in[1];
  const float* b1  = (const float*)d_in[2];
  const float* g1  = (const float*)d_in[3];
  const float* be1 = (const float*)d_in[4];
  const float* w2  = (const float*)d_in[5];
  const float* b2  = (const float*)d_in[6];
  const float* g2  = (const float*)d_in[7];
  const float* be2 = (const float*)d_in[8];
  const float* w3  = (const float*)d_in[9];
  const float* b3  = (const float*)d_in[10];
  const float* g3  = (const float*)d_in[11];
  const float* be3 = (const float*)d_in[12];
  const float* w4  = (const float*)d_in[13];
  const float* b4  = (const float*)d_in[14];
  const float* g4  = (const float*)d_in[15];
  const float* be4 = (const float*)d_in[16];
  const float* w5  = (const float*)d_in[17];
  const float* b5  = (const float*)d_in[18];
  const float* g5  = (const float*)d_in[19];
  const float* be5 = (const float*)d_in[20];
  const float* w6  = (const float*)d_in[21];
  const float* b6  = (const float*)d_in[22];
  const float* g6  = (const float*)d_in[23];
  const float* be6 = (const float*)d_in[24];
  float* out = (float*)d_out;
  char* ws = (char*)d_ws;

  int*      idxb = (int*)(ws + OFF_IDX);
  float*    xx   = (float*)(ws + OFF_XX);
  float*    Aall = (float*)(ws + OFF_STATS);
  float*    Ball = Aall + NCH_TOT;
  float*    buv  = Ball + NCH_TOT;
  short*    xt   = (short*)(ws + OFF_XT);
  short*    wbb  = (short*)(ws + OFF_WB);
  short*    xcat = (short*)(ws + OFF_XC);
  short*    h5   = (short*)(ws + OFF_H5);
  short*    h6   = (short*)(ws + OFF_H6);
  float*    UVf  = (float*)(ws + OFF_UV);
  float*    xr1  = (float*)(ws + OFF_XR1);
  float*    xr2f = (float*)(ws + OFF_XR2);
  float*    xr3f = (float*)(ws + OFF_XR3);
  unsigned* xr4  = (unsigned*)(ws + OFF_XR4);
  short*    h1   = (short*)(ws + OFF_H1);
  short*    h2   = (short*)(ws + OFF_H2);
  short*    h3   = (short*)(ws + OFF_H3);
  float*    pd    = (float*)(ws + OFF_H3);   // aliases h3; consumed before h3 written
  float*    part  = (float*)(ws + OFF_PART);
  float*    part2 = (float*)(ws + OFF_PART2);

  // init ordered-key max buffer for layer 4 only (key 0 < key(-inf))
  hipMemsetAsync(ws + OFF_XR4, 0, 8388608ull, stream);

  k_xx <<<P1_ / 256, 256, 0, stream>>>(x, xx);
  k_pd <<<dim3(8, 16, 8), 256, 0, stream>>>(x, xx, pd);
  k_sel<<<P1_ / 4, 256, 0, stream>>>(pd, idxb);
  k_xt <<<P1_ / 256, 256, 0, stream>>>(x, xt);
  k_wuv<<<32, 256, 0, stream>>>(w1, b1, wbb + WO1, buv);
  k_wcvt<<<1712, 256, 0, stream>>>(w2, w3, w4, w5, w6, wbb);

  // layer 1 factorized: UV[P1][128] fp32 = [W1a·x | (W1b-W1a)·x + b1]
  k_gemm<64, 128, false, false, false, true, true><<<dim3(2, 64), 256, 0, stream>>>(
      xt, wbb + WO1, buv, nullptr, nullptr, nullptr, (short*)UVf, nullptr);
  // expand: h1 = U[nbr]+V, fused stats partials + raw max -> xr1
  k_expand<<<P1_ / 16, 256, 0, stream>>>(UVf, idxb, h1, xr1, part);
  k_red <<<dim3(1, 32), 256, 0, stream>>>(part, P1_ / 16, part2);
  k_bnab<<<1, 256, 0, stream>>>(part2, 32, g1, be1, Aall + SO1, Ball + SO1, 1.f / P2_);

  // layer 2: act(h1) x w2 -> h2 (pure GEMM, epilogue offloaded to k_maxh)
  k_gemm<64, 64, true, false, false, true, false><<<dim3(1, P2_ / 128), 256, 0, stream>>>(
      h1, wbb + WO2, b2, Aall + SO1, Ball + SO1, nullptr, h2, nullptr);
  k_maxh<64><<<P1_ / 32, 256, 0, stream>>>(h2, xr2f, part);
  k_red <<<dim3(1, 32), 256, 0, stream>>>(part, P1_ / 32, part2);
  k_bnab<<<1, 256, 0, stream>>>(part2, 32, g2, be2, Aall + SO2, Ball + SO2, 1.f / P2_);

  // layer 3: act(h2) x w3 -> h3 (pure GEMM, epilogue offloaded to k_maxh)
  k_gemm<64, 128, true, false, false, true, false><<<dim3(2, P2_ / 128), 256, 0, stream>>>(
      h2, wbb + WO3, b3, Aall + SO2, Ball + SO2, nullptr, h3, nullptr);
  k_maxh<128><<<P1_ / 16, 256, 0, stream>>>(h3, xr3f, part);
  k_red <<<dim3(2, 32), 256, 0, stream>>>(part, P1_ / 16, part2);
  k_bnab<<<2, 256, 0, stream>>>(part2, 32, g3, be3, Aall + SO3, Ball + SO3, 1.f / P2_);

  // activate h3 once (in place) so layer 4 stages with zero per-element VALU
  k_act<128><<<P2_ * 128 / 2048, 256, 0, stream>>>(h3, Aall + SO3, Ball + SO3);

  // layer 4: act(h3) x w4 -> NO h4 store; fused raw max + stats (from staged buffer)
  k_gemm<128, 256, false, true, true, false, false><<<dim3(4, P2_ / 128), 256, 0, stream>>>(
      h3, wbb + WO4, b4, nullptr, nullptr, part, nullptr, xr4);
  k_red <<<dim3(4, 32), 256, 0, stream>>>(part, P2_ / 128, part2);
  k_bnab<<<4, 256, 0, stream>>>(part2, 32, g4, be4, Aall + SO4, Ball + SO4, 1.f / P2_);

  // assemble xcat from raw maxes with BN+lrelu
  k_xcat<<<P1_ * 128 / 256, 256, 0, stream>>>(xr1, xr2f, xr3f, xr4, Aall, Ball, xcat);

  // layer 5: xcat x w5 -> h5 + stats (NB=64: direct)
  k_gemm<512, 256, false, true, false, true, false><<<dim3(4, P1_ / 128), 256, 0, stream>>>(
      xcat, wbb + WO5, b5, nullptr, nullptr, part, h5, nullptr);
  k_bnab<<<4, 256, 0, stream>>>(part, P1_ / 128, g5, be5, Aall + SO5, Ball + SO5, 1.f / P1_);

  // activate h5 once (in place) so layer 6 stages with zero per-element VALU
  k_act<256><<<P1_ * 256 / 2048, 256, 0, stream>>>(h5, Aall + SO5, Ball + SO5);

  // layer 6: act(h5) x w6 -> h6 + stats
  k_gemm<256, 1024, false, true, false, true, false><<<dim3(16, P1_ / 128), 256, 0, stream>>>(
      h5, wbb + WO6, b6, nullptr, nullptr, part, h6, nullptr);
  k_bnab<<<16, 256, 0, stream>>>(part, P1_ / 128, g6, be6, Aall + SO6, Ball + SO6, 1.f / P1_);
  k_apply_out<<<P1_ * 256 / 256, 256, 0, stream>>>(h6, Aall + SO6, Ball + SO6, out);

  (void)in_sizes; (void)n_in; (void)out_size; (void)ws_size;
}

// Round 12
// 400.355 us; speedup vs baseline: 1.1272x; 1.0135x over previous
//
#include <hip/hip_runtime.h>
#include <hip/hip_bf16.h>
#include <math.h>

#define B_ 8
#define D_ 60
#define N_ 1024
#define K_ 20
#define P1_ 8192      // B*N
#define P2_ 163840    // B*N*K

typedef __attribute__((ext_vector_type(8))) short bf16x8;
typedef __attribute__((ext_vector_type(4))) short bf16x4;
typedef __attribute__((ext_vector_type(4))) float f32x4;

__device__ inline float b2f(short s) { return __uint_as_float(((unsigned)(unsigned short)s) << 16); }
__device__ inline short f2b(float f) { __hip_bfloat16 h = __float2bfloat16(f); return *(short*)&h; }
// order-preserving float<->uint key (for atomicMax on float values)
__device__ inline unsigned fenc(float f) { unsigned b = __float_as_uint(f); return (b & 0x80000000u) ? ~b : (b | 0x80000000u); }
__device__ inline float fdec(unsigned k) { return __uint_as_float((k & 0x80000000u) ? (k ^ 0x80000000u) : ~k); }

// async global->LDS, 16B per lane; lds dest = wave-uniform base + lane*16
__device__ __forceinline__ void gl16(const short* g, short* l) {
  __builtin_amdgcn_global_load_lds(
      (const __attribute__((address_space(1))) unsigned int*)g,
      (__attribute__((address_space(3))) unsigned int*)l, 16, 0, 0);
}

// ---- workspace layout (bytes), all 256-aligned ----
#define OFF_IDX   0ull          // int[P1][20] = 655360
#define OFF_XX    655360ull     // float[P1]
#define OFF_STATS 688128ull     // A[1792], B[1792], buv[128]
#define OFF_XT    720896ull     // bf16[P1][64] = 1MB
#define OFF_WB    1769472ull    // bf16 weights (wuv at WO1)
#define OFF_XC    2662400ull    // bf16[P1][512] = 8MB
#define OFF_H5    11051008ull   // bf16[P1][256] = 4MB
#define OFF_H6    15245312ull   // bf16[P1][1024] = 16MB
#define OFF_UV    32022528ull   // fp32[P1][128] = 4MB  (U | V)
#define OFF_XR1   36216832ull   // fp32[P1][64] = 2MB   raw max layer1
#define OFF_XR2   38313984ull   // fp32[P1][64] = 2MB   raw max layer2 (plain stores)
#define OFF_XR3   40411136ull   // fp32[P1][128] = 4MB  raw max layer3 (plain stores)
#define OFF_XR4   44605440ull   // uint[P1][256] = 8MB  ordered-key max layer4 (atomics)
#define OFF_H1    52994048ull   // bf16[P2][64] = 20MB
#define OFF_H2    73965568ull   // bf16[P2][64] = 20MB
#define OFF_H3    94937088ull   // bf16[P2][128] = 40MB ; pd (33.5MB fp32) aliases here
#define OFF_PART  136880128ull  // float partial stats, max 4*1280*128*4 = 2.62MB
#define OFF_PART2 139501568ull  // float stage-2 partials, 64KB
// end ~139.6 MiB

#define WO1 0
#define WO2 8192
#define WO3 12288
#define WO4 20480
#define WO5 53248
#define WO6 184320

#define SO1 0
#define SO2 64
#define SO3 128
#define SO4 256
#define SO5 512
#define SO6 768
#define NCH_TOT 1792

// ---------------- xx[bn] = sum_d x^2 ----------------
__global__ __launch_bounds__(256) void k_xx(const float* __restrict__ x,
                                            float* __restrict__ xx) {
  int bn = blockIdx.x * 256 + threadIdx.x;
  int b = bn >> 10, n = bn & 1023;
  const float* xb = x + (size_t)b * D_ * N_ + n;
  float s = 0.f;
  for (int d = 0; d < D_; ++d) { float v = xb[(size_t)d * N_]; s += v * v; }
  xx[bn] = s;
}

// ---------------- pd[b][n][m] = 2*dot - xx_n - xx_m ; tiled fp32 ----------------
__global__ __launch_bounds__(256) void k_pd(const float* __restrict__ x,
                                            const float* __restrict__ xx,
                                            float* __restrict__ pd) {
  __shared__ float lnn[D_][64];
  __shared__ float lmm[D_][128];
  int tid = threadIdx.x;
  int m0 = blockIdx.x * 128, n0 = blockIdx.y * 64, b = blockIdx.z;
  const float* xb = x + (size_t)b * D_ * N_;
  #pragma unroll
  for (int i = 0; i < 15; ++i) {
    int idx = tid + i * 256;
    int d = idx >> 6, col = idx & 63;
    lnn[d][col] = xb[(size_t)d * N_ + n0 + col];
  }
  #pragma unroll
  for (int i = 0; i < 30; ++i) {
    int idx = tid + i * 256;
    int d = idx >> 7, col = idx & 127;
    lmm[d][col] = xb[(size_t)d * N_ + m0 + col];
  }
  __syncthreads();
  int tn = tid >> 5, tm = tid & 31;
  float acc[8][4];
  #pragma unroll
  for (int i = 0; i < 8; ++i)
    #pragma unroll
    for (int j = 0; j < 4; ++j) acc[i][j] = 0.f;
  for (int d = 0; d < D_; ++d) {
    f32x4 mv  = *(const f32x4*)&lmm[d][tm * 4];
    f32x4 nva = *(const f32x4*)&lnn[d][tn * 8];
    f32x4 nvb = *(const f32x4*)&lnn[d][tn * 8 + 4];
    #pragma unroll
    for (int i = 0; i < 4; ++i)
      #pragma unroll
      for (int j = 0; j < 4; ++j) {
        acc[i][j]     = fmaf(nva[i], mv[j], acc[i][j]);
        acc[4 + i][j] = fmaf(nvb[i], mv[j], acc[4 + i][j]);
      }
  }
  const float* xxb = xx + b * 1024;
  f32x4 xxm = *(const f32x4*)(xxb + m0 + tm * 4);
  #pragma unroll
  for (int i = 0; i < 8; ++i) {
    int n = n0 + tn * 8 + i;
    float xxn = xxb[n];
    f32x4 o;
    #pragma unroll
    for (int j = 0; j < 4; ++j) o[j] = 2.f * acc[i][j] - xxn - xxm[j];
    *(f32x4*)(pd + ((size_t)(b * 1024 + n) * 1024) + m0 + tm * 4) = o;
  }
}

// ---------------- selection: one wave per point, top-20 ----------------
__global__ __launch_bounds__(256) void k_sel(const float* __restrict__ pd,
                                             int* __restrict__ idxb) {
  int tid = threadIdx.x;
  int wave = tid >> 6, lane = tid & 63;
  int bn = blockIdx.x * 4 + wave;
  const float* row = pd + (size_t)bn * 1024;
  int mbase = lane * 16;
  f32x4 r0 = *(const f32x4*)(row + mbase);
  f32x4 r1 = *(const f32x4*)(row + mbase + 4);
  f32x4 r2 = *(const f32x4*)(row + mbase + 8);
  f32x4 r3 = *(const f32x4*)(row + mbase + 12);
  float v[16];
  #pragma unroll
  for (int j = 0; j < 4; ++j) { v[j] = r0[j]; v[4 + j] = r1[j]; v[8 + j] = r2[j]; v[12 + j] = r3[j]; }
  int* outp = idxb + (size_t)bn * K_;
  for (int kk = 0; kk < K_; ++kk) {
    float bv = v[0]; int bj = 0;
    #pragma unroll
    for (int j = 1; j < 16; ++j)
      if (v[j] > bv) { bv = v[j]; bj = j; }
    int bi = mbase + bj;
    #pragma unroll
    for (int off = 1; off < 64; off <<= 1) {
      float ov = __shfl_xor(bv, off);
      int   oi = __shfl_xor(bi, off);
      if (ov > bv || (ov == bv && oi < bi)) { bv = ov; bi = oi; }
    }
    if (lane == 0) outp[kk] = bi;
    #pragma unroll
    for (int j = 0; j < 16; ++j)
      if (bi == mbase + j) v[j] = -INFINITY;
  }
}

// ---------------- xt: [B][60][N] fp32 -> [P1][64] bf16 (pad 4 zeros) ----------------
__global__ __launch_bounds__(256) void k_xt(const float* __restrict__ x,
                                            short* __restrict__ xt) {
  int bn = blockIdx.x * 256 + threadIdx.x;
  int b = bn >> 10, n = bn & 1023;
  const float* xb = x + (size_t)b * D_ * N_ + n;
  short* row = xt + (size_t)bn * 64;
  for (int c = 0; c < 60; ++c) row[c] = f2b(xb[(size_t)c * N_]);
  row[60] = 0; row[61] = 0; row[62] = 0; row[63] = 0;
}

// ---------------- wuv: rows 0..63 = W1a (nbr-ctr part), 64..127 = W1b - W1a ----------------
__global__ __launch_bounds__(256) void k_wuv(const float* __restrict__ w1,
                                             const float* __restrict__ b1,
                                             short* __restrict__ wuv,
                                             float* __restrict__ buv) {
  int t = blockIdx.x * 256 + threadIdx.x;  // 8192
  int o = t >> 6, c = t & 63;
  float v = 0.f;
  if (o < 64) { if (c < 60) v = w1[o * 120 + c]; }
  else { int o2 = o - 64; if (c < 60) v = w1[o2 * 120 + 60 + c] - w1[o2 * 120 + c]; }
  wuv[t] = f2b(v);
  if (t < 128) buv[t] = (t < 64) ? 0.f : b1[t - 64];
}

// ---------------- convert w2..w6 fp32 -> bf16 ----------------
__global__ __launch_bounds__(256) void k_wcvt(const float* __restrict__ w2,
                                              const float* __restrict__ w3,
                                              const float* __restrict__ w4,
                                              const float* __restrict__ w5,
                                              const float* __restrict__ w6,
                                              short* __restrict__ wbase) {
  int t = blockIdx.x * 256 + threadIdx.x;
  if (t < 4096) wbase[WO2 + t] = f2b(w2[t]);
  else if (t < 12288) wbase[WO3 + (t - 4096)] = f2b(w3[t - 4096]);
  else if (t < 45056) wbase[WO4 + (t - 12288)] = f2b(w4[t - 12288]);
  else if (t < 176128) wbase[WO5 + (t - 45056)] = f2b(w5[t - 45056]);
  else if (t < 438272) wbase[WO6 + (t - 176128)] = f2b(w6[t - 176128]);
}

// ---------------- standalone BN+lrelu, in place on bf16 [rows][C] ----------------
template <int C>
__global__ __launch_bounds__(256) void k_act(short* __restrict__ h,
                                             const float* __restrict__ A,
                                             const float* __restrict__ Bp) {
  int t = blockIdx.x * 256 + threadIdx.x;
  int c0 = (t & (C / 8 - 1)) * 8;
  bf16x8 v = *(bf16x8*)(h + (size_t)t * 8);
  f32x4 a0 = *(const f32x4*)(A + c0), a1 = *(const f32x4*)(A + c0 + 4);
  f32x4 b0 = *(const f32x4*)(Bp + c0), b1 = *(const f32x4*)(Bp + c0 + 4);
  #pragma unroll
  for (int j = 0; j < 8; ++j) {
    float aj = j < 4 ? a0[j] : a1[j - 4];
    float bj = j < 4 ? b0[j] : b1[j - 4];
    float f = b2f(v[j]) * aj + bj;
    f = f >= 0.f ? f : 0.2f * f;
    v[j] = f2b(f);
  }
  *(bf16x8*)(h + (size_t)t * 8) = v;
}

// ---------------- streaming max-over-k + BN stat partials from stored h ----------------
template <int C>
__global__ __launch_bounds__(256) void k_maxh(const short* __restrict__ h,
                                              float* __restrict__ xrf,
                                              float* __restrict__ part) {
  constexpr int TPP = C / 8;            // threads per point
  constexpr int PTS = 256 / TPP;        // points per block
  __shared__ float lsS[256 * 8];
  __shared__ float lsQ[256 * 8];
  int tid = threadIdx.x;
  int lp = tid / TPP;
  int c0 = (tid % TPP) * 8;
  int pt = blockIdx.x * PTS + lp;
  const short* hp = h + (size_t)pt * K_ * C + c0;
  float mx[8], sm[8], sq[8];
  #pragma unroll
  for (int j = 0; j < 8; ++j) { mx[j] = -INFINITY; sm[j] = 0.f; sq[j] = 0.f; }
  for (int k = 0; k < K_; ++k) {
    bf16x8 v = *(const bf16x8*)(hp + (size_t)k * C);
    #pragma unroll
    for (int j = 0; j < 8; ++j) {
      float f = b2f(v[j]);
      mx[j] = fmaxf(mx[j], f);
      sm[j] += f; sq[j] += f * f;
    }
  }
  f32x4 m0, m1;
  #pragma unroll
  for (int j = 0; j < 4; ++j) { m0[j] = mx[j]; m1[j] = mx[4 + j]; }
  *(f32x4*)(xrf + (size_t)pt * C + c0) = m0;
  *(f32x4*)(xrf + (size_t)pt * C + c0 + 4) = m1;
  #pragma unroll
  for (int j = 0; j < 8; ++j) { lsS[tid * 8 + j] = sm[j]; lsQ[tid * 8 + j] = sq[j]; }
  __syncthreads();
  if (tid < C) {
    int ci = tid >> 3, e = tid & 7;
    float s = 0.f, q = 0.f;
    #pragma unroll
    for (int p = 0; p < PTS; ++p) {
      s += lsS[(p * TPP + ci) * 8 + e];
      q += lsQ[(p * TPP + ci) * 8 + e];
    }
    size_t base = ((size_t)(tid >> 6) * gridDim.x + blockIdx.x) * 128;
    part[base + (tid & 63)] = s;
    part[base + 64 + (tid & 63)] = q;
  }
}

// ---------------- tiled MFMA GEMM: block 128p x 64co, LDS-staged A and W ----------------
// APPLY=true (L2/L3): R9's proven VGPR staging with pad-72 rows.
// APPLY=false (L1/L4/L5/L6): global_load_lds width-16 staging into LINEAR PK=64 rows
// with rule-#21 both-sides XOR swizzle. WMAX (layer 4) stages acc fp32 in two 64-row
// halves inside the A region; max scan vectorized f32x4 on wave 1, stats accumulated
// in wave-0 registers across halves (no LDS atomics, no extra barriers).
template <int K, int COUT, bool APPLY, bool STATS, bool WMAX, bool HSTORE, bool F32OUT>
__global__ __launch_bounds__(256) void k_gemm(const short* __restrict__ in,
                                              const short* __restrict__ wb,
                                              const float* __restrict__ bias,
                                              const float* __restrict__ Ain,
                                              const float* __restrict__ Bin,
                                              float* __restrict__ part,
                                              short* __restrict__ out,
                                              unsigned* __restrict__ umax) {
  constexpr int PANEL = 64;
  constexpr int NPAN = K / PANEL;
  constexpr int CPR = PANEL / 8;            // 16B chunks per panel row (=8)
  constexpr int CSH = 3;
  constexpr bool GL = !APPLY;               // async gl16 path (linear + XOR swizzle)
  constexpr int PK = GL ? 64 : 72;          // LDS row stride (elements)
  constexpr int KS = PANEL / 32;            // MFMA k-steps per panel (=2)
  constexpr int NX = COUT / 64;             // co-chunks (gridDim.x)
  constexpr int ABYTES = 128 * PK * 2;
  constexpr int SA = (WMAX && ABYTES < 17664) ? 17664 : ABYTES;  // holds [64][68] f32
  __shared__ __align__(16) char smem[SA + 64 * PK * 2 + 512];
  short* ldsA = (short*)smem;
  short* ldsW = (short*)(smem + SA);
  float* ls = (float*)(smem + SA + 64 * PK * 2);
  int tid = threadIdx.x;
  int w = tid >> 6, lane = tid & 63;
  int ln = lane & 15, quad = lane >> 4;
  const int rl = lane >> 3;
  const int c16 = (lane & 7) ^ rl;          // inverse-swizzled source slot (GL)
  const int xsl = ln & 7;                   // read-side XOR (GL)
  // XCD-bijective swizzle: all co-chunks of a row-panel land consecutively on one XCD
  int bid = blockIdx.y * NX + blockIdx.x;
  int tot = NX * gridDim.y;
  int gid = (bid & 7) * (tot >> 3) + (bid >> 3);
  int bxx = gid % NX;
  int rp = gid / NX;
  int co0 = bxx * 64;
  const short* srcA = in + (size_t)rp * 128 * K;
  const short* srcW = wb + (size_t)co0 * K;

  f32x4 acc[4][2];
  #pragma unroll
  for (int m = 0; m < 4; ++m)
    #pragma unroll
    for (int t = 0; t < 2; ++t) acc[m][t] = (f32x4){0.f, 0.f, 0.f, 0.f};

  for (int pan = 0; pan < NPAN; ++pan) {
    int kp = pan * PANEL;
    if (pan) __syncthreads();
    if constexpr (GL) {
      // A: 16 chunks of 8 rows, async direct-to-LDS (linear dest, swizzled source)
      #pragma unroll
      for (int i = 0; i < 4; ++i) {
        int ch = w * 4 + i;
        gl16(srcA + (size_t)(ch * 8 + rl) * K + kp + c16 * 8, ldsA + ch * 512);
      }
      // W: 8 chunks of 8 rows
      #pragma unroll
      for (int i = 0; i < 2; ++i) {
        int ch = w * 2 + i;
        gl16(srcW + (size_t)(ch * 8 + rl) * K + kp + c16 * 8, ldsW + ch * 512);
      }
    } else {
      // stage input panel 128 x PANEL (coalesced: 16B/lane), fused BN+lrelu
      #pragma unroll
      for (int i = 0; i < CPR / 2; ++i) {
        int g = i * 256 + tid;
        int row = g >> CSH, c = g & (CPR - 1);
        bf16x8 v = *(const bf16x8*)(srcA + (size_t)row * K + kp + c * 8);
        f32x4 a0 = *(const f32x4*)(Ain + kp + c * 8);
        f32x4 a1 = *(const f32x4*)(Ain + kp + c * 8 + 4);
        f32x4 b0 = *(const f32x4*)(Bin + kp + c * 8);
        f32x4 b1 = *(const f32x4*)(Bin + kp + c * 8 + 4);
        #pragma unroll
        for (int j = 0; j < 8; ++j) {
          float aj = j < 4 ? a0[j] : a1[j - 4];
          float bj = j < 4 ? b0[j] : b1[j - 4];
          float f = b2f(v[j]) * aj + bj;
          f = f >= 0.f ? f : 0.2f * f;
          v[j] = f2b(f);
        }
        *(bf16x8*)(ldsA + row * PK + c * 8) = v;
      }
      // stage weight panel 64 x PANEL
      #pragma unroll
      for (int i = 0; i < CPR / 4; ++i) {
        int g = i * 256 + tid;
        int row = g >> CSH, c = g & (CPR - 1);
        *(bf16x8*)(ldsW + row * PK + c * 8) =
            *(const bf16x8*)(srcW + (size_t)row * K + kp + c * 8);
      }
    }
    __syncthreads();
    #pragma unroll
    for (int ks = 0; ks < KS; ++ks) {
      bf16x8 a[4], bfr[2];
      const int off = GL ? (((ks * 4 + quad) ^ xsl) * 8) : (ks * 32 + quad * 8);
      #pragma unroll
      for (int m = 0; m < 4; ++m)
        a[m] = *(const bf16x8*)(ldsW + (m * 16 + ln) * PK + off);
      #pragma unroll
      for (int t = 0; t < 2; ++t)
        bfr[t] = *(const bf16x8*)(ldsA + (w * 32 + t * 16 + ln) * PK + off);
      #pragma unroll
      for (int m = 0; m < 4; ++m)
        #pragma unroll
        for (int t = 0; t < 2; ++t)
          acc[m][t] = __builtin_amdgcn_mfma_f32_16x16x32_bf16(a[m], bfr[t], acc[m][t], 0, 0, 0);
    }
  }
  // epilogue: bias
  #pragma unroll
  for (int m = 0; m < 4; ++m) {
    f32x4 bs = *(const f32x4*)(bias + co0 + m * 16 + quad * 4);
    #pragma unroll
    for (int t = 0; t < 2; ++t)
      #pragma unroll
      for (int r = 0; r < 4; ++r) acc[m][t][r] += bs[r];
  }
  if (HSTORE) {
    #pragma unroll
    for (int m = 0; m < 4; ++m)
      #pragma unroll
      for (int t = 0; t < 2; ++t) {
        int p = rp * 128 + w * 32 + t * 16 + ln;
        if (F32OUT) {
          *(f32x4*)((float*)out + (size_t)p * COUT + co0 + m * 16 + quad * 4) = acc[m][t];
        } else {
          bf16x4 o;
          #pragma unroll
          for (int r = 0; r < 4; ++r) o[r] = f2b(acc[m][t][r]);
          *(bf16x4*)(out + (size_t)p * COUT + co0 + m * 16 + quad * 4) = o;
        }
      }
  }
  // stats via shfl reduce (layers 5/6: STATS without WMAX)
  if (STATS && !WMAX) {
    __syncthreads();
    if (tid < 128) ls[tid] = 0.f;
    __syncthreads();
    #pragma unroll
    for (int m = 0; m < 4; ++m)
      #pragma unroll
      for (int r = 0; r < 4; ++r) {
        float v0 = acc[m][0][r], v1 = acc[m][1][r];
        float s = v0 + v1, ss = v0 * v0 + v1 * v1;
        #pragma unroll
        for (int off = 1; off < 16; off <<= 1) {
          s += __shfl_xor(s, off); ss += __shfl_xor(ss, off);
        }
        if (ln == 0) {
          atomicAdd(&ls[m * 16 + quad * 4 + r], s);
          atomicAdd(&ls[64 + m * 16 + quad * 4 + r], ss);
        }
      }
    __syncthreads();
    if (tid < 128)
      part[((size_t)bxx * gridDim.y + rp) * 128 + tid] = ls[tid];
  }
  // fused raw max over k (+ stats): stage acc fp32 in two 64-row halves;
  // wave 1 does vectorized f32x4 max scan + atomicMax, wave 0 accumulates
  // column sums/ssq in registers across both halves (no LDS atomics).
  if (WMAX) {
    float* m32 = (float*)smem;  // [64][68] fp32, reuses A region
    f32x4 wsum = (f32x4){0.f, 0.f, 0.f, 0.f};
    f32x4 wssq = (f32x4){0.f, 0.f, 0.f, 0.f};
    const int scq = tid & 15;          // col-quad (stats, wave 0)
    const int srg = tid >> 4;          // row-group 0..3 (stats, wave 0)
    #pragma unroll
    for (int half = 0; half < 2; ++half) {
      __syncthreads();
      if ((w >> 1) == half) {
        int lw = w & 1;
        #pragma unroll
        for (int m = 0; m < 4; ++m)
          #pragma unroll
          for (int t = 0; t < 2; ++t)
            *(f32x4*)(m32 + (size_t)(lw * 32 + t * 16 + ln) * 68 + m * 16 + quad * 4) = acc[m][t];
      }
      __syncthreads();
      if (w == 1) {
        // max-over-k scan, f32x4: 4 candidate groups x 16 col-quads
        int u = tid - 64;
        int r0 = rp * 128 + half * 64;
        int pt0 = r0 / 20;
        int ptg = pt0 + (u >> 4);
        int cq = (u & 15) * 4;
        int rs = ptg * 20 - r0, re = rs + 20;
        rs = rs < 0 ? 0 : rs;
        re = re > 64 ? 64 : re;
        if (rs < re) {
          f32x4 mv = (f32x4){-INFINITY, -INFINITY, -INFINITY, -INFINITY};
          for (int r = rs; r < re; ++r) {
            f32x4 v = *(const f32x4*)(m32 + (size_t)r * 68 + cq);
            #pragma unroll
            for (int j = 0; j < 4; ++j) mv[j] = fmaxf(mv[j], v[j]);
          }
          #pragma unroll
          for (int j = 0; j < 4; ++j)
            atomicMax(&umax[(size_t)ptg * COUT + co0 + cq + j], fenc(mv[j]));
        }
      }
      if (STATS && w == 0) {
        // 16 rows per thread of its col-quad, f32x4
        #pragma unroll
        for (int r = 0; r < 16; ++r) {
          f32x4 v = *(const f32x4*)(m32 + (size_t)(srg * 16 + r) * 68 + scq * 4);
          #pragma unroll
          for (int j = 0; j < 4; ++j) { wsum[j] += v[j]; wssq[j] += v[j] * v[j]; }
        }
      }
    }
    if (STATS && w == 0) {
      // reduce over the 4 row-groups (lane stride 16 within wave 0)
      #pragma unroll
      for (int off = 16; off < 64; off <<= 1) {
        #pragma unroll
        for (int j = 0; j < 4; ++j) {
          wsum[j] += __shfl_xor(wsum[j], off);
          wssq[j] += __shfl_xor(wssq[j], off);
        }
      }
      if (tid < 16) {
        float* pp = part + ((size_t)bxx * gridDim.y + rp) * 128;
        *(f32x4*)(pp + scq * 4) = wsum;
        *(f32x4*)(pp + 64 + scq * 4) = wssq;
      }
    }
  }
}

// ---------------- expand: h1[(n,k),c] = U[nbr,c] + V[n,c]; fused stats + max ----------------
__global__ __launch_bounds__(256) void k_expand(const float* __restrict__ UVf,
                                                const int* __restrict__ idxb,
                                                short* __restrict__ h1,
                                                float* __restrict__ xr1,
                                                float* __restrict__ part) {
  int tid = threadIdx.x;
  int lp = tid >> 4;
  int c0 = (tid & 15) * 4;
  int pt = blockIdx.x * 16 + lp;
  int base = (pt >> 10) << 10;
  f32x4 V = *(const f32x4*)(UVf + (size_t)pt * 128 + 64 + c0);
  f32x4 sum = (f32x4){0.f, 0.f, 0.f, 0.f};
  f32x4 ssq = (f32x4){0.f, 0.f, 0.f, 0.f};
  f32x4 mx = (f32x4){-INFINITY, -INFINITY, -INFINITY, -INFINITY};
  const int* ip = idxb + (size_t)pt * K_;
  size_t hb = (size_t)pt * K_ * 64 + c0;
  for (int k = 0; k < K_; ++k) {
    int nb = base + ip[k];
    f32x4 U = *(const f32x4*)(UVf + (size_t)nb * 128 + c0);
    bf16x4 o;
    #pragma unroll
    for (int j = 0; j < 4; ++j) {
      float h = U[j] + V[j];
      mx[j] = fmaxf(mx[j], U[j]);
      sum[j] += h; ssq[j] += h * h;
      o[j] = f2b(h);
    }
    *(bf16x4*)(h1 + hb + (size_t)k * 64) = o;
  }
  f32x4 xo;
  #pragma unroll
  for (int j = 0; j < 4; ++j) xo[j] = mx[j] + V[j];
  *(f32x4*)(xr1 + (size_t)pt * 64 + c0) = xo;
  __shared__ float ls[2048];
  *(f32x4*)(ls + tid * 4) = sum;
  *(f32x4*)(ls + 1024 + tid * 4) = ssq;
  __syncthreads();
  if (tid < 32) {
    int cl = tid & 15;
    bool issq = tid >= 16;
    const float* src = ls + (issq ? 1024 : 0);
    f32x4 s = (f32x4){0.f, 0.f, 0.f, 0.f};
    #pragma unroll
    for (int g = 0; g < 16; ++g) {
      f32x4 v = *(const f32x4*)(src + (g * 16 + cl) * 4);
      s[0] += v[0]; s[1] += v[1]; s[2] += v[2]; s[3] += v[3];
    }
    *(f32x4*)(part + (size_t)blockIdx.x * 128 + (issq ? 64 : 0) + cl * 4) = s;
  }
}

// ---------------- stage-1 reduction: part[cc][NB][128] -> part2[cc][32][128] ----------------
__global__ __launch_bounds__(256) void k_red(const float* __restrict__ part, int NB,
                                             float* __restrict__ part2) {
  int cc = blockIdx.x, by = blockIdx.y;
  int tid = threadIdx.x;
  int rg = tid >> 5;
  int c4 = (tid & 31) * 4;
  int chunk = NB >> 5;
  const float* p = part + ((size_t)cc * NB + (size_t)by * chunk) * 128;
  f32x4 acc = (f32x4){0.f, 0.f, 0.f, 0.f};
  for (int r = rg; r < chunk; r += 8) {
    f32x4 v = *(const f32x4*)(p + (size_t)r * 128 + c4);
    acc[0] += v[0]; acc[1] += v[1]; acc[2] += v[2]; acc[3] += v[3];
  }
  __shared__ float lds[1024];
  *(f32x4*)(lds + tid * 4) = acc;
  __syncthreads();
  if (tid < 32) {
    f32x4 s = (f32x4){0.f, 0.f, 0.f, 0.f};
    #pragma unroll
    for (int g = 0; g < 8; ++g) {
      f32x4 v = *(const f32x4*)(lds + (g * 32 + tid) * 4);
      s[0] += v[0]; s[1] += v[1]; s[2] += v[2]; s[3] += v[3];
    }
    *(f32x4*)(part2 + ((size_t)cc * 32 + by) * 128 + tid * 4) = s;
  }
}

// ---------------- reduce partials -> A = g*rsqrt(var+eps), B = be - mean*A ----------------
__global__ __launch_bounds__(256) void k_bnab(const float* __restrict__ part, int NB,
                                              const float* __restrict__ g,
                                              const float* __restrict__ be,
                                              float* __restrict__ A,
                                              float* __restrict__ Bp, float inv) {
  __shared__ float red[256];
  int tid = threadIdx.x;
  int j = tid & 127, h = tid >> 7;
  const float* p = part + (size_t)blockIdx.x * NB * 128;
  float s = 0.f;
  for (int bx = h; bx < NB; bx += 2) s += p[(size_t)bx * 128 + j];
  red[tid] = s;
  __syncthreads();
  if (tid < 128) red[tid] = red[tid] + red[tid + 128];
  __syncthreads();
  if (tid < 64) {
    int c = blockIdx.x * 64 + tid;
    float m = red[tid] * inv;
    float v = red[64 + tid] * inv - m * m;
    float a = g[c] * rsqrtf(v + 1e-5f);
    A[c] = a; Bp[c] = be[c] - m * a;
  }
}

// ---------------- xcat: decode raw maxes, apply BN+lrelu, pack [P1][512] bf16 ----------------
__global__ __launch_bounds__(256) void k_xcat(const float* __restrict__ xr1,
                                              const float* __restrict__ xr2f,
                                              const float* __restrict__ xr3f,
                                              const unsigned* __restrict__ xr4,
                                              const float* __restrict__ A,
                                              const float* __restrict__ Bp,
                                              short* __restrict__ xcat) {
  int t = blockIdx.x * 256 + threadIdx.x;  // P1*128
  int p = t >> 7, cq = t & 127;
  int c0 = cq * 4;
  f32x4 v;
  if (c0 < 64) {
    v = *(const f32x4*)(xr1 + (size_t)p * 64 + c0);
  } else if (c0 < 128) {
    v = *(const f32x4*)(xr2f + (size_t)p * 64 + (c0 - 64));
  } else if (c0 < 256) {
    v = *(const f32x4*)(xr3f + (size_t)p * 128 + (c0 - 128));
  } else {
    const unsigned* src = xr4 + (size_t)p * 256;
    int cc = c0 - 256;
    #pragma unroll
    for (int j = 0; j < 4; ++j) v[j] = fdec(src[cc + j]);
  }
  f32x4 a = *(const f32x4*)(A + c0);
  f32x4 b = *(const f32x4*)(Bp + c0);
  bf16x4 o;
  #pragma unroll
  for (int j = 0; j < 4; ++j) {
    float f = v[j] * a[j] + b[j];
    f = f >= 0.f ? f : 0.2f * f;
    o[j] = f2b(f);
  }
  *(bf16x4*)(xcat + (size_t)p * 512 + c0) = o;
}

// ---------------- final: BN+lrelu bf16 [P1][1024] -> fp32 out ----------------
__global__ __launch_bounds__(256) void k_apply_out(const short* __restrict__ h,
                                                   const float* __restrict__ A,
                                                   const float* __restrict__ Bp,
                                                   float* __restrict__ out) {
  int t = blockIdx.x * 256 + threadIdx.x;
  int c0 = (t & 255) * 4;
  f32x4 a = *(const f32x4*)(A + c0);
  f32x4 b = *(const f32x4*)(Bp + c0);
  bf16x4 v = *(const bf16x4*)(h + (size_t)t * 4);
  f32x4 o;
  #pragma unroll
  for (int r = 0; r < 4; ++r) {
    float f = b2f(v[r]) * a[r] + b[r];
    o[r] = f >= 0.f ? f : 0.2f * f;
  }
  *(f32x4*)(out + (size_t)t * 4) = o;
}

extern "C" void kernel_launch(void* const* d_in, const int* in_sizes, int n_in,
                              void* d_out, int out_size, void* d_ws, size_t ws_size,
                              hipStream_t stream) {
  const float* x   = (const float*)d_in[0];
  const float* w1  = (const float*)d_in[1];
  const float* b1  = (const float*)d_in[2];
  const float* g1  = (const float*)d_in[3];
  const float* be1 = (const float*)d_in[4];
  const float* w2  = (const float*)d_in[5];
  const float* b2  = (const float*)d_in[6];
  const float* g2  = (const float*)d_in[7];
  const float* be2 = (const float*)d_in[8];
  const float* w3  = (const float*)d_in[9];
  const float* b3  = (const float*)d_in[10];
  const float* g3  = (const float*)d_in[11];
  const float* be3 = (const float*)d_in[12];
  const float* w4  = (const float*)d_in[13];
  const float* b4  = (const float*)d_in[14];
  const float* g4  = (const float*)d_in[15];
  const float* be4 = (const float*)d_in[16];
  const float* w5  = (const float*)d_in[17];
  const float* b5  = (const float*)d_in[18];
  const float* g5  = (const float*)d_in[19];
  const float* be5 = (const float*)d_in[20];
  const float* w6  = (const float*)d_in[21];
  const float* b6  = (const float*)d_in[22];
  const float* g6  = (const float*)d_in[23];
  const float* be6 = (const float*)d_in[24];
  float* out = (float*)d_out;
  char* ws = (char*)d_ws;

  int*      idxb = (int*)(ws + OFF_IDX);
  float*    xx   = (float*)(ws + OFF_XX);
  float*    Aall = (float*)(ws + OFF_STATS);
  float*    Ball = Aall + NCH_TOT;
  float*    buv  = Ball + NCH_TOT;
  short*    xt   = (short*)(ws + OFF_XT);
  short*    wbb  = (short*)(ws + OFF_WB);
  short*    xcat = (short*)(ws + OFF_XC);
  short*    h5   = (short*)(ws + OFF_H5);
  short*    h6   = (short*)(ws + OFF_H6);
  float*    UVf  = (float*)(ws + OFF_UV);
  float*    xr1  = (float*)(ws + OFF_XR1);
  float*    xr2f = (float*)(ws + OFF_XR2);
  float*    xr3f = (float*)(ws + OFF_XR3);
  unsigned* xr4  = (unsigned*)(ws + OFF_XR4);
  short*    h1   = (short*)(ws + OFF_H1);
  short*    h2   = (short*)(ws + OFF_H2);
  short*    h3   = (short*)(ws + OFF_H3);
  float*    pd    = (float*)(ws + OFF_H3);   // aliases h3; consumed before h3 written
  float*    part  = (float*)(ws + OFF_PART);
  float*    part2 = (float*)(ws + OFF_PART2);

  // init ordered-key max buffer for layer 4 only (key 0 < key(-inf))
  hipMemsetAsync(ws + OFF_XR4, 0, 8388608ull, stream);

  k_xx <<<P1_ / 256, 256, 0, stream>>>(x, xx);
  k_pd <<<dim3(8, 16, 8), 256, 0, stream>>>(x, xx, pd);
  k_sel<<<P1_ / 4, 256, 0, stream>>>(pd, idxb);
  k_xt <<<P1_ / 256, 256, 0, stream>>>(x, xt);
  k_wuv<<<32, 256, 0, stream>>>(w1, b1, wbb + WO1, buv);
  k_wcvt<<<1712, 256, 0, stream>>>(w2, w3, w4, w5, w6, wbb);

  // layer 1 factorized: UV[P1][128] fp32 = [W1a·x | (W1b-W1a)·x + b1]
  k_gemm<64, 128, false, false, false, true, true><<<dim3(2, 64), 256, 0, stream>>>(
      xt, wbb + WO1, buv, nullptr, nullptr, nullptr, (short*)UVf, nullptr);
  // expand: h1 = U[nbr]+V, fused stats partials + raw max -> xr1
  k_expand<<<P1_ / 16, 256, 0, stream>>>(UVf, idxb, h1, xr1, part);
  k_red <<<dim3(1, 32), 256, 0, stream>>>(part, P1_ / 16, part2);
  k_bnab<<<1, 256, 0, stream>>>(part2, 32, g1, be1, Aall + SO1, Ball + SO1, 1.f / P2_);

  // layer 2: act(h1) x w2 -> h2 (pure GEMM, epilogue offloaded to k_maxh)
  k_gemm<64, 64, true, false, false, true, false><<<dim3(1, P2_ / 128), 256, 0, stream>>>(
      h1, wbb + WO2, b2, Aall + SO1, Ball + SO1, nullptr, h2, nullptr);
  k_maxh<64><<<P1_ / 32, 256, 0, stream>>>(h2, xr2f, part);
  k_red <<<dim3(1, 32), 256, 0, stream>>>(part, P1_ / 32, part2);
  k_bnab<<<1, 256, 0, stream>>>(part2, 32, g2, be2, Aall + SO2, Ball + SO2, 1.f / P2_);

  // layer 3: act(h2) x w3 -> h3 (pure GEMM, epilogue offloaded to k_maxh)
  k_gemm<64, 128, true, false, false, true, false><<<dim3(2, P2_ / 128), 256, 0, stream>>>(
      h2, wbb + WO3, b3, Aall + SO2, Ball + SO2, nullptr, h3, nullptr);
  k_maxh<128><<<P1_ / 16, 256, 0, stream>>>(h3, xr3f, part);
  k_red <<<dim3(2, 32), 256, 0, stream>>>(part, P1_ / 16, part2);
  k_bnab<<<2, 256, 0, stream>>>(part2, 32, g3, be3, Aall + SO3, Ball + SO3, 1.f / P2_);

  // activate h3 once (in place) so layer 4 stages with zero per-element VALU
  k_act<128><<<P2_ * 128 / 2048, 256, 0, stream>>>(h3, Aall + SO3, Ball + SO3);

  // layer 4: act(h3) x w4 -> NO h4 store; fused raw max + stats (from staged buffer)
  k_gemm<128, 256, false, true, true, false, false><<<dim3(4, P2_ / 128), 256, 0, stream>>>(
      h3, wbb + WO4, b4, nullptr, nullptr, part, nullptr, xr4);
  k_red <<<dim3(4, 32), 256, 0, stream>>>(part, P2_ / 128, part2);
  k_bnab<<<4, 256, 0, stream>>>(part2, 32, g4, be4, Aall + SO4, Ball + SO4, 1.f / P2_);

  // assemble xcat from raw maxes with BN+lrelu
  k_xcat<<<P1_ * 128 / 256, 256, 0, stream>>>(xr1, xr2f, xr3f, xr4, Aall, Ball, xcat);

  // layer 5: xcat x w5 -> h5 + stats (NB=64: direct)
  k_gemm<512, 256, false, true, false, true, false><<<dim3(4, P1_ / 128), 256, 0, stream>>>(
      xcat, wbb + WO5, b5, nullptr, nullptr, part, h5, nullptr);
  k_bnab<<<4, 256, 0, stream>>>(part, P1_ / 128, g5, be5, Aall + SO5, Ball + SO5, 1.f / P1_);

  // activate h5 once (in place) so layer 6 stages without NX-duplicated apply
  k_act<256><<<P1_ * 256 / 2048, 256, 0, stream>>>(h5, Aall + SO5, Ball + SO5);

  // layer 6: act(h5) x w6 -> h6 + stats
  k_gemm<256, 1024, false, true, false, true, false><<<dim3(16, P1_ / 128), 256, 0, stream>>>(
      h5, wbb + WO6, b6, nullptr, nullptr, part, h6, nullptr);
  k_bnab<<<16, 256, 0, stream>>>(part, P1_ / 128, g6, be6, Aall + SO6, Ball + SO6, 1.f / P1_);
  k_apply_out<<<P1_ * 256 / 256, 256, 0, stream>>>(h6, Aall + SO6, Ball + SO6, out);

  (void)in_sizes; (void)n_in; (void)out_size; (void)ws_size;
}